// Round 1
// baseline (3527.383 us; speedup 1.0000x reference)
//
#include <hip/hip_runtime.h>

#define DEV __device__ __forceinline__

DEV float elu1(float x) { return x > 0.f ? x + 1.f : __expf(x); }

// ---------------------------------------------------------------------------
// Convolutions: direct conv, NCHW in, NCHW out ([b, oc, l] with l = y*32+x).
// Each thread: 4 horizontally-consecutive pixels; 8 output channels per block.
// Input plane staged per-channel in LDS (32x33 padded).
// ---------------------------------------------------------------------------
template<int K>
DEV void conv_body(const float* __restrict__ src,   // + b*256*1024
                   const float* __restrict__ W,     // + oc0*256*K*K
                   float* __restrict__ outp,        // + (b*256+oc_glob0)*1024
                   float* plane, int tid)
{
    constexpr int P = K / 2;
    const int y  = tid >> 3;          // 0..31
    const int x0 = (tid & 7) * 4;     // 0,4,...,28
    float acc[4][8];
#pragma unroll
    for (int e = 0; e < 4; ++e)
#pragma unroll
        for (int j = 0; j < 8; ++j) acc[e][j] = 0.f;

    for (int c = 0; c < 256; ++c) {
        __syncthreads();
        {
            float4 v = *(const float4*)(src + c*1024 + tid*4);
            plane[y*33 + x0 + 0] = v.x;
            plane[y*33 + x0 + 1] = v.y;
            plane[y*33 + x0 + 2] = v.z;
            plane[y*33 + x0 + 3] = v.w;
        }
        __syncthreads();
        const float* Wc = W + c*K*K;
#pragma unroll
        for (int dy = 0; dy < K; ++dy) {
            const int yy = y + dy - P;
            const bool yok = (unsigned)yy < 32u;
            float rv[K + 3];
#pragma unroll
            for (int m = 0; m < K + 3; ++m) {
                int xx = x0 - P + m;
                rv[m] = (yok && (unsigned)xx < 32u) ? plane[yy*33 + xx] : 0.f;
            }
#pragma unroll
            for (int dx = 0; dx < K; ++dx) {
                float w[8];
#pragma unroll
                for (int j = 0; j < 8; ++j)
                    w[j] = Wc[j*256*K*K + dy*K + dx];
#pragma unroll
                for (int e = 0; e < 4; ++e) {
                    float v = rv[dx + e];
#pragma unroll
                    for (int j = 0; j < 8; ++j) acc[e][j] += v * w[j];
                }
            }
        }
    }
#pragma unroll
    for (int j = 0; j < 8; ++j) {
        float4 r = make_float4(acc[0][j], acc[1][j], acc[2][j], acc[3][j]);
        *(float4*)(outp + j*1024 + y*32 + x0) = r;
    }
}

__global__ __launch_bounds__(256) void conv_q_kernel(const float* __restrict__ x,
                                                     const float* __restrict__ Wq,
                                                     float* __restrict__ q)
{
    __shared__ float plane[32*33];
    const int tid = threadIdx.x;
    const int bx = blockIdx.x;           // 8 b * 32 groups = 256
    const int b = bx >> 5;
    const int oc0 = (bx & 31) * 8;
    conv_body<3>(x + (size_t)b*256*1024, Wq + (size_t)oc0*256*9,
                 q + ((size_t)b*256 + oc0)*1024, plane, tid);
}

__global__ __launch_bounds__(256) void conv_kv_kernel(
    const float* __restrict__ src,
    const float* __restrict__ Wk1, const float* __restrict__ Wk3,
    const float* __restrict__ Wk5, const float* __restrict__ Wk7,
    const float* __restrict__ Wv1, const float* __restrict__ Wv3,
    const float* __restrict__ Wv5, const float* __restrict__ Wv7,
    float* __restrict__ kout, float* __restrict__ vout)
{
    __shared__ float plane[32*33];
    const int tid = threadIdx.x;
    const int bx = blockIdx.x;           // 8 b * 8 slots * 8 groups = 512
    const int g    = bx & 7;
    const int slot = (bx >> 3) & 7;      // head + 4*isv
    const int b    = bx >> 6;
    const int head = slot & 3;
    const int isv  = slot >> 2;
    const int oc0  = g * 8;
    const float* srcb = src + (size_t)b*256*1024;
    float* outp = (isv ? vout : kout) + ((size_t)b*256 + head*64 + oc0)*1024;
    switch (head) {
    case 0:  conv_body<1>(srcb, (isv?Wv1:Wk1) + (size_t)oc0*256*1,  outp, plane, tid); break;
    case 1:  conv_body<3>(srcb, (isv?Wv3:Wk3) + (size_t)oc0*256*9,  outp, plane, tid); break;
    case 2:  conv_body<5>(srcb, (isv?Wv5:Wk5) + (size_t)oc0*256*25, outp, plane, tid); break;
    default: conv_body<7>(srcb, (isv?Wv7:Wk7) + (size_t)oc0*256*49, outp, plane, tid); break;
    }
}

// ---------------------------------------------------------------------------
// QK^T: per (b,h), scores[l][s] = (q . k) * 0.125, written to vis [b,h,l,s].
// l-tile 64, s-tile 64; thread computes 4x4 scores; LDS tiles [64][68] floats.
// ---------------------------------------------------------------------------
__global__ __launch_bounds__(256) void qk_kernel(const float* __restrict__ q,
                                                 const float* __restrict__ k,
                                                 float* __restrict__ vis)
{
    __shared__ float4 Qt4[64*17];
    __shared__ float4 Kt4[64*17];
    float* Qt = (float*)Qt4;
    float* Kt = (float*)Kt4;
    const int t = threadIdx.x;
    const int bx = blockIdx.x;           // 8b * 4h * 16 ltiles = 512
    const int b  = bx >> 6;
    const int h  = (bx >> 4) & 3;
    const int l0 = (bx & 15) * 64;
    const float* qb = q + ((size_t)b*256 + h*64)*1024 + l0;
    const float* kb = k + ((size_t)b*256 + h*64)*1024;
    {
        int d = t >> 2, r0 = (t & 3) * 16;
#pragma unroll
        for (int mm = 0; mm < 4; ++mm) {
            float4 v = *(const float4*)(qb + d*1024 + r0 + mm*4);
            Qt[(r0+mm*4+0)*68 + d] = v.x;
            Qt[(r0+mm*4+1)*68 + d] = v.y;
            Qt[(r0+mm*4+2)*68 + d] = v.z;
            Qt[(r0+mm*4+3)*68 + d] = v.w;
        }
    }
    const int ig = t >> 4;   // i = ig*4+ii
    const int sg = t & 15;   // s = sg*4+j
    float* visbase = vis + ((size_t)((b*4 + h)*1024 + l0 + ig*4))*1024;
    for (int st = 0; st < 16; ++st) {
        __syncthreads();
        {
            int d = t >> 2, r0 = (t & 3) * 16;
#pragma unroll
            for (int mm = 0; mm < 4; ++mm) {
                float4 v = *(const float4*)(kb + d*1024 + st*64 + r0 + mm*4);
                Kt[(r0+mm*4+0)*68 + d] = v.x;
                Kt[(r0+mm*4+1)*68 + d] = v.y;
                Kt[(r0+mm*4+2)*68 + d] = v.z;
                Kt[(r0+mm*4+3)*68 + d] = v.w;
            }
        }
        __syncthreads();
        float acc[4][4];
#pragma unroll
        for (int ii = 0; ii < 4; ++ii)
#pragma unroll
            for (int j = 0; j < 4; ++j) acc[ii][j] = 0.f;
#pragma unroll
        for (int dq = 0; dq < 16; ++dq) {
            float4 qv[4], kv[4];
#pragma unroll
            for (int ii = 0; ii < 4; ++ii) qv[ii] = Qt4[(ig*4+ii)*17 + dq];
#pragma unroll
            for (int j = 0; j < 4; ++j) kv[j] = Kt4[(sg*4+j)*17 + dq];
#pragma unroll
            for (int ii = 0; ii < 4; ++ii)
#pragma unroll
                for (int j = 0; j < 4; ++j)
                    acc[ii][j] += qv[ii].x*kv[j].x + qv[ii].y*kv[j].y
                                + qv[ii].z*kv[j].z + qv[ii].w*kv[j].w;
        }
#pragma unroll
        for (int ii = 0; ii < 4; ++ii) {
            float4 r = make_float4(acc[ii][0]*0.125f, acc[ii][1]*0.125f,
                                   acc[ii][2]*0.125f, acc[ii][3]*0.125f);
            *(float4*)(visbase + (size_t)ii*1024 + st*64 + sg*4) = r;
        }
    }
}

// ---------------------------------------------------------------------------
// Row softmax in-place over vis rows of 1024.
// ---------------------------------------------------------------------------
__global__ __launch_bounds__(256) void softmax_kernel(float* __restrict__ vis)
{
    const int t = threadIdx.x;
    float4* p = (float4*)(vis + (size_t)blockIdx.x * 1024);
    float4 v = p[t];
    float m = fmaxf(fmaxf(v.x, v.y), fmaxf(v.z, v.w));
#pragma unroll
    for (int off = 1; off < 64; off <<= 1) m = fmaxf(m, __shfl_xor(m, off));
    __shared__ float sm[4];
    __shared__ float ss[4];
    const int wid = t >> 6, lane = t & 63;
    if (lane == 0) sm[wid] = m;
    __syncthreads();
    m = fmaxf(fmaxf(sm[0], sm[1]), fmaxf(sm[2], sm[3]));
    float4 e;
    e.x = __expf(v.x - m); e.y = __expf(v.y - m);
    e.z = __expf(v.z - m); e.w = __expf(v.w - m);
    float s = e.x + e.y + e.z + e.w;
#pragma unroll
    for (int off = 1; off < 64; off <<= 1) s += __shfl_xor(s, off);
    if (lane == 0) ss[wid] = s;
    __syncthreads();
    s = ss[0] + ss[1] + ss[2] + ss[3];
    float inv = 1.f / s;
    e.x *= inv; e.y *= inv; e.z *= inv; e.w *= inv;
    p[t] = e;
}

// ---------------------------------------------------------------------------
// Linear attention: KV partials (raw sums) + Ksum partials over s-chunks.
// ---------------------------------------------------------------------------
__global__ __launch_bounds__(256) void kv_kernel(const float* __restrict__ k,
                                                 const float* __restrict__ v,
                                                 float* __restrict__ KVp,
                                                 float* __restrict__ Ksump)
{
    __shared__ float4 Kt4[64*17];
    __shared__ float4 Vt4[64*16];
    float* Kt = (float*)Kt4;
    float* Vt = (float*)Vt4;
    const int t = threadIdx.x;
    const int bx = blockIdx.x;           // b*16 + h*4 + ch = 128
    const int b = bx >> 4, h = (bx >> 2) & 3, ch = bx & 3;
    const float* kb = k + ((size_t)b*256 + h*64)*1024 + ch*256;
    const float* vb = v + ((size_t)b*256 + h*64)*1024 + ch*256;
    const int d = t >> 2, v0 = (t & 3) * 16;
    float4 acc[4];
#pragma unroll
    for (int j = 0; j < 4; ++j) acc[j] = make_float4(0.f, 0.f, 0.f, 0.f);
    float ks = 0.f;
    for (int st = 0; st < 4; ++st) {
        __syncthreads();
        {
            int dd = t >> 2, r0 = (t & 3) * 16;
#pragma unroll
            for (int mm = 0; mm < 4; ++mm) {
                float4 kv = *(const float4*)(kb + dd*1024 + st*64 + r0 + mm*4);
                Kt[(r0+mm*4+0)*68 + dd] = elu1(kv.x);
                Kt[(r0+mm*4+1)*68 + dd] = elu1(kv.y);
                Kt[(r0+mm*4+2)*68 + dd] = elu1(kv.z);
                Kt[(r0+mm*4+3)*68 + dd] = elu1(kv.w);
                float4 vv = *(const float4*)(vb + dd*1024 + st*64 + r0 + mm*4);
                Vt[(r0+mm*4+0)*64 + dd] = vv.x;
                Vt[(r0+mm*4+1)*64 + dd] = vv.y;
                Vt[(r0+mm*4+2)*64 + dd] = vv.z;
                Vt[(r0+mm*4+3)*64 + dd] = vv.w;
            }
        }
        __syncthreads();
#pragma unroll 8
        for (int s = 0; s < 64; ++s) {
            float kf = Kt[s*68 + d];
            const float4* vp = (const float4*)(Vt + s*64 + v0);
#pragma unroll
            for (int j = 0; j < 4; ++j) {
                float4 vv = vp[j];
                acc[j].x += kf*vv.x; acc[j].y += kf*vv.y;
                acc[j].z += kf*vv.z; acc[j].w += kf*vv.w;
            }
        }
        if (t < 64) {
#pragma unroll 8
            for (int s = 0; s < 64; ++s) ks += Kt[s*68 + t];
        }
    }
    float* op = KVp + ((size_t)((ch*32 + b*4 + h)*64 + d))*64 + v0;
#pragma unroll
    for (int j = 0; j < 4; ++j) ((float4*)op)[j] = acc[j];
    if (t < 64) Ksump[(size_t)(ch*32 + b*4 + h)*64 + t] = ks;
}

// ---------------------------------------------------------------------------
// msg[b,l,h,v] = Z * sum_d Qf[d] * KV[h,d,v],  Z = 1/(Qf.Ksum + 1e-6)
// ---------------------------------------------------------------------------
__global__ __launch_bounds__(256) void msg_kernel(const float* __restrict__ q,
                                                  const float* __restrict__ KVp,
                                                  const float* __restrict__ Ksump,
                                                  float* __restrict__ msg)
{
    __shared__ float4 kvl4[4*1028];      // per-h stride 4112 floats (pad)
    __shared__ float ksl[4*65];
    float* kvl = (float*)kvl4;
    const int t = threadIdx.x;
    const int bx = blockIdx.x;           // b*16 + ltile = 128
    const int b = bx >> 4;
    const int l0 = (bx & 15) * 64;
    for (int m = 0; m < 64; ++m) {
        int idx = t + 256*m;
        int hh = idx >> 12, dd = (idx >> 6) & 63, vv = idx & 63;
        float s = 0.f;
#pragma unroll
        for (int ch = 0; ch < 4; ++ch)
            s += KVp[(size_t)((ch*32 + b*4))*4096 + idx];
        kvl[hh*4112 + dd*64 + vv] = s;
    }
    {
        int hh = t >> 6, dd = t & 63;
        float s = 0.f;
#pragma unroll
        for (int ch = 0; ch < 4; ++ch)
            s += Ksump[(size_t)(ch*32 + b*4)*64 + t];
        ksl[hh*65 + dd] = s;
    }
    __syncthreads();
    const int h = t & 3, l = l0 + (t >> 2);
    const float* qb = q + ((size_t)b*256 + h*64)*1024 + l;
    float qf[64];
#pragma unroll
    for (int dd = 0; dd < 64; ++dd) qf[dd] = elu1(qb[dd*1024]);
    float zd = 1e-6f;
#pragma unroll
    for (int dd = 0; dd < 64; ++dd) zd += qf[dd] * ksl[h*65 + dd];
    const float Z = 1.f / zd;
    float* op = msg + ((size_t)(b*1024 + l))*256 + h*64;
    for (int c0 = 0; c0 < 64; c0 += 16) {
        float4 a[4];
#pragma unroll
        for (int j = 0; j < 4; ++j) a[j] = make_float4(0.f, 0.f, 0.f, 0.f);
#pragma unroll
        for (int dd = 0; dd < 64; ++dd) {
            float qv = qf[dd];
            const float4* kp = (const float4*)(kvl + h*4112 + dd*64 + c0);
#pragma unroll
            for (int j = 0; j < 4; ++j) {
                float4 kk = kp[j];
                a[j].x += qv*kk.x; a[j].y += qv*kk.y;
                a[j].z += qv*kk.z; a[j].w += qv*kk.w;
            }
        }
#pragma unroll
        for (int j = 0; j < 4; ++j) {
            a[j].x *= Z; a[j].y *= Z; a[j].z *= Z; a[j].w *= Z;
            ((float4*)(op + c0))[j] = a[j];
        }
    }
}

// ---------------------------------------------------------------------------
// merge: msgm = LN1(msg @ Wm). 16 rows per block; thread = one output column.
// ---------------------------------------------------------------------------
__global__ __launch_bounds__(256) void merge_ln1_kernel(const float* __restrict__ msg,
                                                        const float* __restrict__ Wm,
                                                        const float* __restrict__ g1,
                                                        const float* __restrict__ b1,
                                                        float* __restrict__ msgm)
{
    __shared__ float4 mL4[16*65];        // stride 260 floats
    __shared__ float mv[32];
    float* mL = (float*)mL4;
    const int t = threadIdx.x;
    const size_t base = (size_t)blockIdx.x * 16;   // 512 blocks
    {
        int r = t >> 4, cb = t & 15;
#pragma unroll
        for (int j = 0; j < 16; ++j)
            mL[r*260 + cb + 16*j] = msg[(base + r)*256 + cb + 16*j];
    }
    __syncthreads();
    float acc[16];
#pragma unroll
    for (int r = 0; r < 16; ++r) acc[r] = 0.f;
    for (int i = 0; i < 256; i += 4) {
        float w0 = Wm[(size_t)(i+0)*256 + t];
        float w1 = Wm[(size_t)(i+1)*256 + t];
        float w2 = Wm[(size_t)(i+2)*256 + t];
        float w3 = Wm[(size_t)(i+3)*256 + t];
#pragma unroll
        for (int r = 0; r < 16; ++r) {
            float4 m4 = mL4[r*65 + (i >> 2)];
            acc[r] += m4.x*w0 + m4.y*w1 + m4.z*w2 + m4.w*w3;
        }
    }
    __syncthreads();
#pragma unroll
    for (int r = 0; r < 16; ++r) mL[r*260 + t] = acc[r];
    __syncthreads();
    {
        int wid = t >> 6, lane = t & 63;
#pragma unroll
        for (int rr = 0; rr < 4; ++rr) {
            int r = wid*4 + rr;
            float s1 = 0.f, s2 = 0.f;
#pragma unroll
            for (int m = 0; m < 4; ++m) {
                float vv = mL[r*260 + lane + 64*m];
                s1 += vv; s2 += vv*vv;
            }
#pragma unroll
            for (int off = 1; off < 64; off <<= 1) {
                s1 += __shfl_xor(s1, off);
                s2 += __shfl_xor(s2, off);
            }
            if (lane == 0) {
                float mean = s1 * (1.f/256.f);
                float var  = s2 * (1.f/256.f) - mean*mean;
                mv[r*2]   = mean;
                mv[r*2+1] = rsqrtf(var + 1e-5f);
            }
        }
    }
    __syncthreads();
    const float gg = g1[t], bb = b1[t];
#pragma unroll
    for (int r = 0; r < 16; ++r) {
        float val = (mL[r*260 + t] - mv[r*2]) * mv[r*2+1] * gg + bb;
        msgm[(base + r)*256 + t] = val;
    }
}

// ---------------------------------------------------------------------------
// FF: hidden = relu([x_nhwc, msgm] @ W1); y = LN2(hidden @ W2); out = x + y.
// ---------------------------------------------------------------------------
__global__ __launch_bounds__(256) void ff_kernel(const float* __restrict__ x,
                                                 const float* __restrict__ msgm,
                                                 const float* __restrict__ W1,
                                                 const float* __restrict__ W2,
                                                 const float* __restrict__ g2,
                                                 const float* __restrict__ b2,
                                                 float* __restrict__ out)
{
    __shared__ float4 cL4[16*129];       // stride 516 floats
    __shared__ float mv[32];
    float* cL = (float*)cL4;
    const int t = threadIdx.x;
    const size_t base = (size_t)blockIdx.x * 16;   // 512 blocks
    const int b  = (int)(base >> 10);
    const int l0 = (int)(base & 1023);
    {
        const float4* xp = (const float4*)(x + ((size_t)b*256 + t)*1024 + l0);
#pragma unroll
        for (int jj = 0; jj < 4; ++jj) {
            float4 v = xp[jj];
            cL[(jj*4+0)*516 + t] = v.x;
            cL[(jj*4+1)*516 + t] = v.y;
            cL[(jj*4+2)*516 + t] = v.z;
            cL[(jj*4+3)*516 + t] = v.w;
        }
#pragma unroll
        for (int r = 0; r < 16; ++r)
            cL[r*516 + 256 + t] = msgm[(base + r)*256 + t];
    }
    __syncthreads();
    float a0[16], a1[16];
#pragma unroll
    for (int r = 0; r < 16; ++r) { a0[r] = 0.f; a1[r] = 0.f; }
    for (int i = 0; i < 512; i += 4) {
        float w0[4], w1[4];
#pragma unroll
        for (int e = 0; e < 4; ++e) {
            w0[e] = W1[(size_t)(i+e)*512 + t];
            w1[e] = W1[(size_t)(i+e)*512 + 256 + t];
        }
#pragma unroll
        for (int r = 0; r < 16; ++r) {
            float4 cv = cL4[r*129 + (i >> 2)];
            a0[r] += cv.x*w0[0] + cv.y*w0[1] + cv.z*w0[2] + cv.w*w0[3];
            a1[r] += cv.x*w1[0] + cv.y*w1[1] + cv.z*w1[2] + cv.w*w1[3];
        }
    }
    __syncthreads();
#pragma unroll
    for (int r = 0; r < 16; ++r) {
        cL[r*516 + t]       = fmaxf(a0[r], 0.f);
        cL[r*516 + 256 + t] = fmaxf(a1[r], 0.f);
    }
    __syncthreads();
    float a2[16];
#pragma unroll
    for (int r = 0; r < 16; ++r) a2[r] = 0.f;
    for (int i = 0; i < 512; i += 4) {
        float w[4];
#pragma unroll
        for (int e = 0; e < 4; ++e) w[e] = W2[(size_t)(i+e)*256 + t];
#pragma unroll
        for (int r = 0; r < 16; ++r) {
            float4 cv = cL4[r*129 + (i >> 2)];
            a2[r] += cv.x*w[0] + cv.y*w[1] + cv.z*w[2] + cv.w*w[3];
        }
    }
    __syncthreads();
#pragma unroll
    for (int r = 0; r < 16; ++r) cL[r*516 + t] = a2[r];
    __syncthreads();
    {
        int wid = t >> 6, lane = t & 63;
#pragma unroll
        for (int rr = 0; rr < 4; ++rr) {
            int r = wid*4 + rr;
            float s1 = 0.f, s2 = 0.f;
#pragma unroll
            for (int m = 0; m < 4; ++m) {
                float vv = cL[r*516 + lane + 64*m];
                s1 += vv; s2 += vv*vv;
            }
#pragma unroll
            for (int off = 1; off < 64; off <<= 1) {
                s1 += __shfl_xor(s1, off);
                s2 += __shfl_xor(s2, off);
            }
            if (lane == 0) {
                float mean = s1 * (1.f/256.f);
                float var  = s2 * (1.f/256.f) - mean*mean;
                mv[r*2]   = mean;
                mv[r*2+1] = rsqrtf(var + 1e-5f);
            }
        }
    }
    __syncthreads();
#pragma unroll
    for (int quad = 0; quad < 4; ++quad) {
        int c = quad*64 + (t >> 2);
        int lch = (t & 3) * 4;
        float gg = g2[c], bb = b2[c];
        float vals[4];
#pragma unroll
        for (int e = 0; e < 4; ++e) {
            int r = lch + e;
            vals[e] = (cL[r*516 + c] - mv[r*2]) * mv[r*2+1] * gg + bb;
        }
        const float4 xv = *(const float4*)(x + ((size_t)b*256 + c)*1024 + l0 + lch);
        float4 o = make_float4(xv.x + vals[0], xv.y + vals[1],
                               xv.z + vals[2], xv.w + vals[3]);
        *(float4*)(out + ((size_t)b*256 + c)*1024 + l0 + lch) = o;
    }
}

// ---------------------------------------------------------------------------
extern "C" void kernel_launch(void* const* d_in, const int* in_sizes, int n_in,
                              void* d_out, int out_size, void* d_ws, size_t ws_size,
                              hipStream_t stream)
{
    const float* x    = (const float*)d_in[0];
    const float* src  = (const float*)d_in[1];
    const float* Wq   = (const float*)d_in[2];
    const float* Wk1  = (const float*)d_in[3];
    const float* Wk3  = (const float*)d_in[4];
    const float* Wk5  = (const float*)d_in[5];
    const float* Wk7  = (const float*)d_in[6];
    const float* Wv1  = (const float*)d_in[7];
    const float* Wv3  = (const float*)d_in[8];
    const float* Wv5  = (const float*)d_in[9];
    const float* Wv7  = (const float*)d_in[10];
    const float* Wm   = (const float*)d_in[11];
    const float* g1   = (const float*)d_in[12];
    const float* b1   = (const float*)d_in[13];
    const float* g2   = (const float*)d_in[14];
    const float* b2   = (const float*)d_in[15];
    const float* W1   = (const float*)d_in[16];
    const float* W2   = (const float*)d_in[17];

    float* out = (float*)d_out;
    float* vis = out + 2097152;          // [b,h,l,s] = 8*4*1024*1024

    float* ws    = (float*)d_ws;
    float* qb    = ws;                   // [b,256,1024]
    float* kb    = ws + 2097152;
    float* vb    = ws + 4194304;
    float* msg   = ws + 6291456;         // [b,l,256]
    float* msgm  = ws + 8388608;         // [b,l,256]
    float* KVp   = ws + 10485760;        // [4][32][64][64]
    float* Ksump = ws + 11010048;        // [4][32][64]

    conv_q_kernel <<<256,  256, 0, stream>>>(x, Wq, qb);
    conv_kv_kernel<<<512,  256, 0, stream>>>(src, Wk1, Wk3, Wk5, Wk7,
                                             Wv1, Wv3, Wv5, Wv7, kb, vb);
    qk_kernel     <<<512,  256, 0, stream>>>(qb, kb, vis);
    softmax_kernel<<<32768,256, 0, stream>>>(vis);
    kv_kernel     <<<128,  256, 0, stream>>>(kb, vb, KVp, Ksump);
    msg_kernel    <<<128,  256, 0, stream>>>(qb, KVp, Ksump, msg);
    merge_ln1_kernel<<<512,256, 0, stream>>>(msg, Wm, g1, b1, msgm);
    ff_kernel     <<<512,  256, 0, stream>>>(x, msgm, W1, W2, g2, b2, out);
}

// Round 2
// 581.215 us; speedup vs baseline: 6.0690x; 6.0690x over previous
//
#include <hip/hip_runtime.h>

#define DEV __device__ __forceinline__

typedef unsigned short u16;
typedef __bf16 bf16x8 __attribute__((ext_vector_type(8)));
typedef float f32x4 __attribute__((ext_vector_type(4)));

DEV float elu1(float x) { return x > 0.f ? x + 1.f : __expf(x); }

DEV u16 f2bf(float f) {
    union { float f; unsigned u; } v; v.f = f;
    unsigned r = v.u + 0x7fffu + ((v.u >> 16) & 1u);
    return (u16)(r >> 16);
}

// ===========================================================================
// Weight repack: all convs -> bf16 MFMA A-fragments, exact lane order.
// Pack layout: frag f (1KB) = 64 lanes x 16B. Sections (KB offsets):
//   q slots 0-3: s*288 ; k-side base 1152, v-side base 3840:
//   +0: K1(32) +32: K3(288) +320: K5(800) +1120: K7(1568). Total 6528 KB.
// Within section: frag rel = (tap*8 + cchunk)*4 + ocgrp.
// Lane l: oc = ocbase + ocgrp*16 + (l&15); c = cchunk*32 + (l>>4)*8 + j.
// ===========================================================================
__global__ __launch_bounds__(256) void repack_kernel(
    const float* __restrict__ Wq,
    const float* __restrict__ Wk1, const float* __restrict__ Wk3,
    const float* __restrict__ Wk5, const float* __restrict__ Wk7,
    const float* __restrict__ Wv1, const float* __restrict__ Wv3,
    const float* __restrict__ Wv5, const float* __restrict__ Wv7,
    u16* __restrict__ wpack)
{
    int gid = blockIdx.x * 256 + threadIdx.x;     // 1632*256 = 417792
    int frag = gid >> 6, l = gid & 63;
    const float* W; int K, ocbase = 0, rel;
    if (frag < 1152) {
        W = Wq; K = 3; int slot = frag / 288; rel = frag % 288; ocbase = slot * 64;
    } else {
        int f = frag - 1152; int side = f / 2688; f %= 2688;
        if (f < 32)        { W = side ? Wv1 : Wk1; K = 1; rel = f; }
        else if (f < 320)  { W = side ? Wv3 : Wk3; K = 3; rel = f - 32; }
        else if (f < 1120) { W = side ? Wv5 : Wk5; K = 5; rel = f - 320; }
        else               { W = side ? Wv7 : Wk7; K = 7; rel = f - 1120; }
    }
    int og = rel & 3, cc = (rel >> 2) & 7, tap = rel >> 5;
    int dy = tap / K, dx = tap % K;
    int oc = ocbase + og * 16 + (l & 15);
    int c0 = cc * 32 + (l >> 4) * 8;
    u16 pk[8];
#pragma unroll
    for (int j = 0; j < 8; ++j)
        pk[j] = f2bf(W[((size_t)(oc * 256 + c0 + j) * K + dy) * K + dx]);
    *(int4*)&wpack[(size_t)frag * 512 + l * 8] = *(const int4*)pk;
}

// ===========================================================================
// MFMA implicit-GEMM conv. Block: 64 oc x 256 px (8 rows). 4 waves, each
// wave M=64 x N=64 (2 rows). LDS B-tile [c_hi4][y14][x40][c_lo8] bf16, zero
// halo; per (tap, c-chunk): 4 global A-frag loads + 4 ds_read_b128 + 16 MFMA.
// ===========================================================================
template<int K>
DEV void conv_mfma_body(const float* __restrict__ srcp,  // + b plane
                        const u16* __restrict__ wsec,    // section base (u16)
                        float* __restrict__ dst,         // oc-stride 1024
                        u16* Bt, int y0, int cch0, int ncc, int t)
{
    constexpr int P = K / 2;
    const int w = t >> 6, l = t & 63;
    const int chi = l >> 4, ln = l & 15;
    const int rowbase = chi * 14 + w * 2 + 3 - P;   // + dy + (n>>1)
    const int colbase = ln + 3 - P;                 // + dx + (n&1)*16
    f32x4 acc[4][4];
#pragma unroll
    for (int m = 0; m < 4; ++m)
#pragma unroll
        for (int n = 0; n < 4; ++n) acc[m][n] = (f32x4){0.f, 0.f, 0.f, 0.f};

    for (int cc = 0; cc < ncc; ++cc) {
        const int ccg = cch0 + cc;
        const int cg0 = ccg * 32;
        __syncthreads();
        // ---- stage source c-chunk into LDS (bf16, transposed, haloed) ----
        for (int u = 0; u < 9; ++u) {
            int unit = t + (u << 8);
            if (unit < 1792) {
                int xv = unit & 31, r = unit >> 5;      // r<56
                int yy = r % 14, ch = r / 14;
                int ygl = y0 - 3 + yy;
                u16 pk[8];
                if ((unsigned)ygl < 32u) {
                    const float* sp = srcp + (size_t)(cg0 + ch * 8) * 1024 + ygl * 32 + xv;
#pragma unroll
                    for (int j = 0; j < 8; ++j) pk[j] = f2bf(sp[j * 1024]);
                } else {
#pragma unroll
                    for (int j = 0; j < 8; ++j) pk[j] = 0;
                }
                *(int4*)&Bt[((ch * 14 + yy) * 40 + xv + 3) * 8] = *(const int4*)pk;
            } else if (unit < 2240) {
                int hu = unit - 1792;
                int hx = hu & 7; int xi = hx < 3 ? hx : hx + 32;
                int r = hu >> 3; int yy = r % 14, ch = r / 14;
                int4 z = {0, 0, 0, 0};
                *(int4*)&Bt[((ch * 14 + yy) * 40 + xi) * 8] = z;
            }
        }
        __syncthreads();
        // ---- taps ----
        for (int dy = 0; dy < K; ++dy) {
#pragma unroll
            for (int dx = 0; dx < K; ++dx) {
                const int tap = dy * K + dx;
                const u16* wp = wsec + ((size_t)(tap * 8 + ccg) * 4) * 512 + l * 8;
                bf16x8 a0 = *(const bf16x8*)(wp);
                bf16x8 a1 = *(const bf16x8*)(wp + 512);
                bf16x8 a2 = *(const bf16x8*)(wp + 1024);
                bf16x8 a3 = *(const bf16x8*)(wp + 1536);
                bf16x8 bf[4];
#pragma unroll
                for (int n = 0; n < 4; ++n) {
                    int row = rowbase + dy + (n >> 1);
                    int col = colbase + dx + (n & 1) * 16;
                    bf[n] = *(const bf16x8*)&Bt[(row * 40 + col) * 8];
                }
#pragma unroll
                for (int n = 0; n < 4; ++n) {
                    acc[0][n] = __builtin_amdgcn_mfma_f32_16x16x32_bf16(a0, bf[n], acc[0][n], 0, 0, 0);
                    acc[1][n] = __builtin_amdgcn_mfma_f32_16x16x32_bf16(a1, bf[n], acc[1][n], 0, 0, 0);
                    acc[2][n] = __builtin_amdgcn_mfma_f32_16x16x32_bf16(a2, bf[n], acc[2][n], 0, 0, 0);
                    acc[3][n] = __builtin_amdgcn_mfma_f32_16x16x32_bf16(a3, bf[n], acc[3][n], 0, 0, 0);
                }
            }
        }
    }
    // ---- epilogue: D row = (l>>4)*4+reg (oc), col = l&15 (px) ----
#pragma unroll
    for (int m = 0; m < 4; ++m)
#pragma unroll
        for (int n = 0; n < 4; ++n) {
            int y = y0 + w * 2 + (n >> 1);
            int px = y * 32 + (n & 1) * 16 + ln;
            int ocb = m * 16 + chi * 4;
#pragma unroll
            for (int r = 0; r < 4; ++r)
                dst[(size_t)(ocb + r) * 1024 + px] = acc[m][n][r];
        }
}

// Job decode: 80 blocks per batch.
//  r<16: q slot r>>2, ytile r&3 (K3, full c)
//  else r2=r-16, side=r2>>5 (0=k,1=v), r3=r2&31:
//   r3<4: K1 head0; r3<8: K3 head1; r3<16: K5 (csplit2); r3<32: K7 (csplit4)
__global__ __launch_bounds__(256) void conv_mfma_kernel(
    const float* __restrict__ x, const float* __restrict__ source,
    const u16* __restrict__ wpack,
    float* __restrict__ qb, float* __restrict__ kb, float* __restrict__ vb,
    float* __restrict__ p5, float* __restrict__ p7)
{
    __shared__ u16 Bt[4 * 14 * 40 * 8];
    const int bx = blockIdx.x, t = threadIdx.x;
    const int b = bx / 80, r = bx % 80;
    if (r < 16) {
        int slot = r >> 2, yt = r & 3;
        conv_mfma_body<3>(x + (size_t)b * 262144,
                          wpack + (size_t)(slot * 288) * 512,
                          qb + ((size_t)b * 256 + slot * 64) * 1024,
                          Bt, yt * 8, 0, 8, t);
        return;
    }
    const int r2 = r - 16, side = r2 >> 5, r3 = r2 & 31;
    const float* sp = source + (size_t)b * 262144;
    float* fin = side ? vb : kb;
    const size_t wkb = 1152 + (size_t)side * 2688;   // KB
    if (r3 < 4) {
        conv_mfma_body<1>(sp, wpack + (wkb + 0) * 512,
                          fin + ((size_t)b * 256) * 1024, Bt, r3 * 8, 0, 8, t);
    } else if (r3 < 8) {
        conv_mfma_body<3>(sp, wpack + (wkb + 32) * 512,
                          fin + ((size_t)b * 256 + 64) * 1024, Bt, (r3 - 4) * 8, 0, 8, t);
    } else if (r3 < 16) {
        int t5 = r3 - 8, cpart = t5 >> 2, yt = t5 & 3;
        conv_mfma_body<5>(sp, wpack + (wkb + 320) * 512,
                          p5 + (((size_t)side * 2 + cpart) * 8 + b) * 65536,
                          Bt, yt * 8, cpart * 4, 4, t);
    } else {
        int t7 = r3 - 16, cpart = t7 >> 2, yt = t7 & 3;
        conv_mfma_body<7>(sp, wpack + (wkb + 1120) * 512,
                          p7 + (((size_t)side * 4 + cpart) * 8 + b) * 65536,
                          Bt, yt * 8, cpart * 2, 2, t);
    }
}

// Sum c-split partials into kb/vb heads 2 (K5) and 3 (K7).
__global__ __launch_bounds__(256) void reduce_kernel(
    const float* __restrict__ p5, const float* __restrict__ p7,
    float* __restrict__ kb, float* __restrict__ vb)
{
    int gid = blockIdx.x * 256 + threadIdx.x;     // 524288 float4 units
    int px4 = gid & 255;
    int rr = gid >> 8;
    int oc = rr & 127, b = (rr >> 7) & 7, side = rr >> 10;
    float* outb = side ? vb : kb;
    if (oc < 64) {
        const float4* a0 = (const float4*)(p5 + (((size_t)side * 2 + 0) * 8 + b) * 65536 + (size_t)oc * 1024) + px4;
        const float4* a1 = (const float4*)(p5 + (((size_t)side * 2 + 1) * 8 + b) * 65536 + (size_t)oc * 1024) + px4;
        float4 u = *a0, v = *a1;
        float4 s = make_float4(u.x + v.x, u.y + v.y, u.z + v.z, u.w + v.w);
        *((float4*)(outb + ((size_t)b * 256 + 128 + oc) * 1024) + px4) = s;
    } else {
        int o7 = oc - 64;
        float4 s = make_float4(0.f, 0.f, 0.f, 0.f);
#pragma unroll
        for (int p = 0; p < 4; ++p) {
            float4 u = *((const float4*)(p7 + (((size_t)side * 4 + p) * 8 + b) * 65536 + (size_t)o7 * 1024) + px4);
            s.x += u.x; s.y += u.y; s.z += u.z; s.w += u.w;
        }
        *((float4*)(outb + ((size_t)b * 256 + 192 + o7) * 1024) + px4) = s;
    }
}

// ---------------------------------------------------------------------------
// QK^T: per (b,h), scores[l][s] = (q . k) * 0.125, written to vis [b,h,l,s].
// ---------------------------------------------------------------------------
__global__ __launch_bounds__(256) void qk_kernel(const float* __restrict__ q,
                                                 const float* __restrict__ k,
                                                 float* __restrict__ vis)
{
    __shared__ float4 Qt4[64*17];
    __shared__ float4 Kt4[64*17];
    float* Qt = (float*)Qt4;
    float* Kt = (float*)Kt4;
    const int t = threadIdx.x;
    const int bx = blockIdx.x;           // 8b * 4h * 16 ltiles = 512
    const int b  = bx >> 6;
    const int h  = (bx >> 4) & 3;
    const int l0 = (bx & 15) * 64;
    const float* qb = q + ((size_t)b*256 + h*64)*1024 + l0;
    const float* kb = k + ((size_t)b*256 + h*64)*1024;
    {
        int d = t >> 2, r0 = (t & 3) * 16;
#pragma unroll
        for (int mm = 0; mm < 4; ++mm) {
            float4 v = *(const float4*)(qb + d*1024 + r0 + mm*4);
            Qt[(r0+mm*4+0)*68 + d] = v.x;
            Qt[(r0+mm*4+1)*68 + d] = v.y;
            Qt[(r0+mm*4+2)*68 + d] = v.z;
            Qt[(r0+mm*4+3)*68 + d] = v.w;
        }
    }
    const int ig = t >> 4;
    const int sg = t & 15;
    float* visbase = vis + ((size_t)((b*4 + h)*1024 + l0 + ig*4))*1024;
    for (int st = 0; st < 16; ++st) {
        __syncthreads();
        {
            int d = t >> 2, r0 = (t & 3) * 16;
#pragma unroll
            for (int mm = 0; mm < 4; ++mm) {
                float4 v = *(const float4*)(kb + d*1024 + st*64 + r0 + mm*4);
                Kt[(r0+mm*4+0)*68 + d] = v.x;
                Kt[(r0+mm*4+1)*68 + d] = v.y;
                Kt[(r0+mm*4+2)*68 + d] = v.z;
                Kt[(r0+mm*4+3)*68 + d] = v.w;
            }
        }
        __syncthreads();
        float acc[4][4];
#pragma unroll
        for (int ii = 0; ii < 4; ++ii)
#pragma unroll
            for (int j = 0; j < 4; ++j) acc[ii][j] = 0.f;
#pragma unroll
        for (int dq = 0; dq < 16; ++dq) {
            float4 qv[4], kv[4];
#pragma unroll
            for (int ii = 0; ii < 4; ++ii) qv[ii] = Qt4[(ig*4+ii)*17 + dq];
#pragma unroll
            for (int j = 0; j < 4; ++j) kv[j] = Kt4[(sg*4+j)*17 + dq];
#pragma unroll
            for (int ii = 0; ii < 4; ++ii)
#pragma unroll
                for (int j = 0; j < 4; ++j)
                    acc[ii][j] += qv[ii].x*kv[j].x + qv[ii].y*kv[j].y
                                + qv[ii].z*kv[j].z + qv[ii].w*kv[j].w;
        }
#pragma unroll
        for (int ii = 0; ii < 4; ++ii) {
            float4 r = make_float4(acc[ii][0]*0.125f, acc[ii][1]*0.125f,
                                   acc[ii][2]*0.125f, acc[ii][3]*0.125f);
            *(float4*)(visbase + (size_t)ii*1024 + st*64 + sg*4) = r;
        }
    }
}

__global__ __launch_bounds__(256) void softmax_kernel(float* __restrict__ vis)
{
    const int t = threadIdx.x;
    float4* p = (float4*)(vis + (size_t)blockIdx.x * 1024);
    float4 v = p[t];
    float m = fmaxf(fmaxf(v.x, v.y), fmaxf(v.z, v.w));
#pragma unroll
    for (int off = 1; off < 64; off <<= 1) m = fmaxf(m, __shfl_xor(m, off));
    __shared__ float sm[4];
    __shared__ float ss[4];
    const int wid = t >> 6, lane = t & 63;
    if (lane == 0) sm[wid] = m;
    __syncthreads();
    m = fmaxf(fmaxf(sm[0], sm[1]), fmaxf(sm[2], sm[3]));
    float4 e;
    e.x = __expf(v.x - m); e.y = __expf(v.y - m);
    e.z = __expf(v.z - m); e.w = __expf(v.w - m);
    float s = e.x + e.y + e.z + e.w;
#pragma unroll
    for (int off = 1; off < 64; off <<= 1) s += __shfl_xor(s, off);
    if (lane == 0) ss[wid] = s;
    __syncthreads();
    s = ss[0] + ss[1] + ss[2] + ss[3];
    float inv = 1.f / s;
    e.x *= inv; e.y *= inv; e.z *= inv; e.w *= inv;
    p[t] = e;
}

__global__ __launch_bounds__(256) void kv_kernel(const float* __restrict__ k,
                                                 const float* __restrict__ v,
                                                 float* __restrict__ KVp,
                                                 float* __restrict__ Ksump)
{
    __shared__ float4 Kt4[64*17];
    __shared__ float4 Vt4[64*16];
    float* Kt = (float*)Kt4;
    float* Vt = (float*)Vt4;
    const int t = threadIdx.x;
    const int bx = blockIdx.x;
    const int b = bx >> 4, h = (bx >> 2) & 3, ch = bx & 3;
    const float* kb = k + ((size_t)b*256 + h*64)*1024 + ch*256;
    const float* vb = v + ((size_t)b*256 + h*64)*1024 + ch*256;
    const int d = t >> 2, v0 = (t & 3) * 16;
    float4 acc[4];
#pragma unroll
    for (int j = 0; j < 4; ++j) acc[j] = make_float4(0.f, 0.f, 0.f, 0.f);
    float ks = 0.f;
    for (int st = 0; st < 4; ++st) {
        __syncthreads();
        {
            int dd = t >> 2, r0 = (t & 3) * 16;
#pragma unroll
            for (int mm = 0; mm < 4; ++mm) {
                float4 kv = *(const float4*)(kb + dd*1024 + st*64 + r0 + mm*4);
                Kt[(r0+mm*4+0)*68 + dd] = elu1(kv.x);
                Kt[(r0+mm*4+1)*68 + dd] = elu1(kv.y);
                Kt[(r0+mm*4+2)*68 + dd] = elu1(kv.z);
                Kt[(r0+mm*4+3)*68 + dd] = elu1(kv.w);
                float4 vv = *(const float4*)(vb + dd*1024 + st*64 + r0 + mm*4);
                Vt[(r0+mm*4+0)*64 + dd] = vv.x;
                Vt[(r0+mm*4+1)*64 + dd] = vv.y;
                Vt[(r0+mm*4+2)*64 + dd] = vv.z;
                Vt[(r0+mm*4+3)*64 + dd] = vv.w;
            }
        }
        __syncthreads();
#pragma unroll 8
        for (int s = 0; s < 64; ++s) {
            float kf = Kt[s*68 + d];
            const float4* vp = (const float4*)(Vt + s*64 + v0);
#pragma unroll
            for (int j = 0; j < 4; ++j) {
                float4 vv = vp[j];
                acc[j].x += kf*vv.x; acc[j].y += kf*vv.y;
                acc[j].z += kf*vv.z; acc[j].w += kf*vv.w;
            }
        }
        if (t < 64) {
#pragma unroll 8
            for (int s = 0; s < 64; ++s) ks += Kt[s*68 + t];
        }
    }
    float* op = KVp + ((size_t)((ch*32 + b*4 + h)*64 + d))*64 + v0;
#pragma unroll
    for (int j = 0; j < 4; ++j) ((float4*)op)[j] = acc[j];
    if (t < 64) Ksump[(size_t)(ch*32 + b*4 + h)*64 + t] = ks;
}

__global__ __launch_bounds__(256) void msg_kernel(const float* __restrict__ q,
                                                  const float* __restrict__ KVp,
                                                  const float* __restrict__ Ksump,
                                                  float* __restrict__ msg)
{
    __shared__ float4 kvl4[4*1028];
    __shared__ float ksl[4*65];
    float* kvl = (float*)kvl4;
    const int t = threadIdx.x;
    const int bx = blockIdx.x;
    const int b = bx >> 4;
    const int l0 = (bx & 15) * 64;
    for (int m = 0; m < 64; ++m) {
        int idx = t + 256*m;
        int hh = idx >> 12, dd = (idx >> 6) & 63, vv = idx & 63;
        float s = 0.f;
#pragma unroll
        for (int ch = 0; ch < 4; ++ch)
            s += KVp[(size_t)((ch*32 + b*4))*4096 + idx];
        kvl[hh*4112 + dd*64 + vv] = s;
    }
    {
        float s = 0.f;
#pragma unroll
        for (int ch = 0; ch < 4; ++ch)
            s += Ksump[(size_t)(ch*32 + b*4)*64 + t];
        ksl[(t >> 6)*65 + (t & 63)] = s;
    }
    __syncthreads();
    const int h = t & 3, l = l0 + (t >> 2);
    const float* qb = q + ((size_t)b*256 + h*64)*1024 + l;
    float qf[64];
#pragma unroll
    for (int dd = 0; dd < 64; ++dd) qf[dd] = elu1(qb[dd*1024]);
    float zd = 1e-6f;
#pragma unroll
    for (int dd = 0; dd < 64; ++dd) zd += qf[dd] * ksl[h*65 + dd];
    const float Z = 1.f / zd;
    float* op = msg + ((size_t)(b*1024 + l))*256 + h*64;
    for (int c0 = 0; c0 < 64; c0 += 16) {
        float4 a[4];
#pragma unroll
        for (int j = 0; j < 4; ++j) a[j] = make_float4(0.f, 0.f, 0.f, 0.f);
#pragma unroll
        for (int dd = 0; dd < 64; ++dd) {
            float qv = qf[dd];
            const float4* kp = (const float4*)(kvl + h*4112 + dd*64 + c0);
#pragma unroll
            for (int j = 0; j < 4; ++j) {
                float4 kk = kp[j];
                a[j].x += qv*kk.x; a[j].y += qv*kk.y;
                a[j].z += qv*kk.z; a[j].w += qv*kk.w;
            }
        }
#pragma unroll
        for (int j = 0; j < 4; ++j) {
            a[j].x *= Z; a[j].y *= Z; a[j].z *= Z; a[j].w *= Z;
            ((float4*)(op + c0))[j] = a[j];
        }
    }
}

__global__ __launch_bounds__(256) void merge_ln1_kernel(const float* __restrict__ msg,
                                                        const float* __restrict__ Wm,
                                                        const float* __restrict__ g1,
                                                        const float* __restrict__ b1,
                                                        float* __restrict__ msgm)
{
    __shared__ float4 mL4[16*65];
    __shared__ float mv[32];
    float* mL = (float*)mL4;
    const int t = threadIdx.x;
    const size_t base = (size_t)blockIdx.x * 16;
    {
        int r = t >> 4, cb = t & 15;
#pragma unroll
        for (int j = 0; j < 16; ++j)
            mL[r*260 + cb + 16*j] = msg[(base + r)*256 + cb + 16*j];
    }
    __syncthreads();
    float acc[16];
#pragma unroll
    for (int r = 0; r < 16; ++r) acc[r] = 0.f;
    for (int i = 0; i < 256; i += 4) {
        float w0 = Wm[(size_t)(i+0)*256 + t];
        float w1 = Wm[(size_t)(i+1)*256 + t];
        float w2 = Wm[(size_t)(i+2)*256 + t];
        float w3 = Wm[(size_t)(i+3)*256 + t];
#pragma unroll
        for (int r = 0; r < 16; ++r) {
            float4 m4 = mL4[r*65 + (i >> 2)];
            acc[r] += m4.x*w0 + m4.y*w1 + m4.z*w2 + m4.w*w3;
        }
    }
    __syncthreads();
#pragma unroll
    for (int r = 0; r < 16; ++r) mL[r*260 + t] = acc[r];
    __syncthreads();
    {
        int wid = t >> 6, lane = t & 63;
#pragma unroll
        for (int rr = 0; rr < 4; ++rr) {
            int r = wid*4 + rr;
            float s1 = 0.f, s2 = 0.f;
#pragma unroll
            for (int m = 0; m < 4; ++m) {
                float vv = mL[r*260 + lane + 64*m];
                s1 += vv; s2 += vv*vv;
            }
#pragma unroll
            for (int off = 1; off < 64; off <<= 1) {
                s1 += __shfl_xor(s1, off);
                s2 += __shfl_xor(s2, off);
            }
            if (lane == 0) {
                float mean = s1 * (1.f/256.f);
                float var  = s2 * (1.f/256.f) - mean*mean;
                mv[r*2]   = mean;
                mv[r*2+1] = rsqrtf(var + 1e-5f);
            }
        }
    }
    __syncthreads();
    const float gg = g1[t], bb = b1[t];
#pragma unroll
    for (int r = 0; r < 16; ++r) {
        float val = (mL[r*260 + t] - mv[r*2]) * mv[r*2+1] * gg + bb;
        msgm[(base + r)*256 + t] = val;
    }
}

__global__ __launch_bounds__(256) void ff_kernel(const float* __restrict__ x,
                                                 const float* __restrict__ msgm,
                                                 const float* __restrict__ W1,
                                                 const float* __restrict__ W2,
                                                 const float* __restrict__ g2,
                                                 const float* __restrict__ b2,
                                                 float* __restrict__ out)
{
    __shared__ float4 cL4[16*129];
    __shared__ float mv[32];
    float* cL = (float*)cL4;
    const int t = threadIdx.x;
    const size_t base = (size_t)blockIdx.x * 16;
    const int b  = (int)(base >> 10);
    const int l0 = (int)(base & 1023);
    {
        const float4* xp = (const float4*)(x + ((size_t)b*256 + t)*1024 + l0);
#pragma unroll
        for (int jj = 0; jj < 4; ++jj) {
            float4 v = xp[jj];
            cL[(jj*4+0)*516 + t] = v.x;
            cL[(jj*4+1)*516 + t] = v.y;
            cL[(jj*4+2)*516 + t] = v.z;
            cL[(jj*4+3)*516 + t] = v.w;
        }
#pragma unroll
        for (int r = 0; r < 16; ++r)
            cL[r*516 + 256 + t] = msgm[(base + r)*256 + t];
    }
    __syncthreads();
    float a0[16], a1[16];
#pragma unroll
    for (int r = 0; r < 16; ++r) { a0[r] = 0.f; a1[r] = 0.f; }
    for (int i = 0; i < 512; i += 4) {
        float w0[4], w1[4];
#pragma unroll
        for (int e = 0; e < 4; ++e) {
            w0[e] = W1[(size_t)(i+e)*512 + t];
            w1[e] = W1[(size_t)(i+e)*512 + 256 + t];
        }
#pragma unroll
        for (int r = 0; r < 16; ++r) {
            float4 cv = cL4[r*129 + (i >> 2)];
            a0[r] += cv.x*w0[0] + cv.y*w0[1] + cv.z*w0[2] + cv.w*w0[3];
            a1[r] += cv.x*w1[0] + cv.y*w1[1] + cv.z*w1[2] + cv.w*w1[3];
        }
    }
    __syncthreads();
#pragma unroll
    for (int r = 0; r < 16; ++r) {
        cL[r*516 + t]       = fmaxf(a0[r], 0.f);
        cL[r*516 + 256 + t] = fmaxf(a1[r], 0.f);
    }
    __syncthreads();
    float a2[16];
#pragma unroll
    for (int r = 0; r < 16; ++r) a2[r] = 0.f;
    for (int i = 0; i < 512; i += 4) {
        float w[4];
#pragma unroll
        for (int e = 0; e < 4; ++e) w[e] = W2[(size_t)(i+e)*256 + t];
#pragma unroll
        for (int r = 0; r < 16; ++r) {
            float4 cv = cL4[r*129 + (i >> 2)];
            a2[r] += cv.x*w[0] + cv.y*w[1] + cv.z*w[2] + cv.w*w[3];
        }
    }
    __syncthreads();
#pragma unroll
    for (int r = 0; r < 16; ++r) cL[r*516 + t] = a2[r];
    __syncthreads();
    {
        int wid = t >> 6, lane = t & 63;
#pragma unroll
        for (int rr = 0; rr < 4; ++rr) {
            int r = wid*4 + rr;
            float s1 = 0.f, s2 = 0.f;
#pragma unroll
            for (int m = 0; m < 4; ++m) {
                float vv = cL[r*516 + lane + 64*m];
                s1 += vv; s2 += vv*vv;
            }
#pragma unroll
            for (int off = 1; off < 64; off <<= 1) {
                s1 += __shfl_xor(s1, off);
                s2 += __shfl_xor(s2, off);
            }
            if (lane == 0) {
                float mean = s1 * (1.f/256.f);
                float var  = s2 * (1.f/256.f) - mean*mean;
                mv[r*2]   = mean;
                mv[r*2+1] = rsqrtf(var + 1e-5f);
            }
        }
    }
    __syncthreads();
#pragma unroll
    for (int quad = 0; quad < 4; ++quad) {
        int c = quad*64 + (t >> 2);
        int lch = (t & 3) * 4;
        float gg = g2[c], bb = b2[c];
        float vals[4];
#pragma unroll
        for (int e = 0; e < 4; ++e) {
            int r = lch + e;
            vals[e] = (cL[r*516 + c] - mv[r*2]) * mv[r*2+1] * gg + bb;
        }
        const float4 xv = *(const float4*)(x + ((size_t)b*256 + c)*1024 + l0 + lch);
        float4 o = make_float4(xv.x + vals[0], xv.y + vals[1],
                               xv.z + vals[2], xv.w + vals[3]);
        *(float4*)(out + ((size_t)b*256 + c)*1024 + l0 + lch) = o;
    }
}

// ---------------------------------------------------------------------------
extern "C" void kernel_launch(void* const* d_in, const int* in_sizes, int n_in,
                              void* d_out, int out_size, void* d_ws, size_t ws_size,
                              hipStream_t stream)
{
    const float* x    = (const float*)d_in[0];
    const float* src  = (const float*)d_in[1];
    const float* Wq   = (const float*)d_in[2];
    const float* Wk1  = (const float*)d_in[3];
    const float* Wk3  = (const float*)d_in[4];
    const float* Wk5  = (const float*)d_in[5];
    const float* Wk7  = (const float*)d_in[6];
    const float* Wv1  = (const float*)d_in[7];
    const float* Wv3  = (const float*)d_in[8];
    const float* Wv5  = (const float*)d_in[9];
    const float* Wv7  = (const float*)d_in[10];
    const float* Wm   = (const float*)d_in[11];
    const float* g1   = (const float*)d_in[12];
    const float* b1   = (const float*)d_in[13];
    const float* g2   = (const float*)d_in[14];
    const float* b2   = (const float*)d_in[15];
    const float* W1   = (const float*)d_in[16];
    const float* W2   = (const float*)d_in[17];

    float* out = (float*)d_out;
    float* vis = out + 2097152;          // [b,h,l,s]

    float* ws    = (float*)d_ws;
    float* qb    = ws;                   // [b,256,1024]
    float* kb    = ws + 2097152;
    float* vb    = ws + 4194304;
    u16*   wpack = (u16*)(ws + 6291456); // 6528 KB packed bf16 weights
    float* p5    = ws + 7962624;         // [side2][part2][b8][64][1024]
    float* p7    = ws + 10059776;        // [side2][part4][b8][64][1024]
    // aliases (used only after reduce_kernel consumed p5/p7):
    float* msg   = ws + 7962624;
    float* msgm  = ws + 10059776;
    float* KVp   = ws + 12156928;
    float* Ksump = ws + 12681216;

    repack_kernel   <<<1632, 256, 0, stream>>>(Wq, Wk1, Wk3, Wk5, Wk7,
                                               Wv1, Wv3, Wv5, Wv7, wpack);
    conv_mfma_kernel<<<640,  256, 0, stream>>>(x, src, wpack, qb, kb, vb, p5, p7);
    reduce_kernel   <<<2048, 256, 0, stream>>>(p5, p7, kb, vb);
    qk_kernel       <<<512,  256, 0, stream>>>(qb, kb, vis);
    softmax_kernel  <<<32768,256, 0, stream>>>(vis);
    kv_kernel       <<<128,  256, 0, stream>>>(kb, vb, KVp, Ksump);
    msg_kernel      <<<128,  256, 0, stream>>>(qb, KVp, Ksump, msg);
    merge_ln1_kernel<<<512,  256, 0, stream>>>(msg, Wm, g1, b1, msgm);
    ff_kernel       <<<512,  256, 0, stream>>>(x, msgm, W1, W2, g2, b2, out);
}

// Round 4
// 353.777 us; speedup vs baseline: 9.9706x; 1.6429x over previous
//
#include <hip/hip_runtime.h>

#define DEV __device__ __forceinline__

typedef unsigned short u16;
typedef unsigned int u32;
typedef __bf16 bf16x8 __attribute__((ext_vector_type(8)));
typedef float f32x4 __attribute__((ext_vector_type(4)));

DEV float elu1(float x) { return x > 0.f ? x + 1.f : __expf(x); }

DEV u16 f2bf(float f) {
    union { float f; unsigned u; } v; v.f = f;
    unsigned r = v.u + 0x7fffu + ((v.u >> 16) & 1u);
    return (u16)(r >> 16);
}

// ===========================================================================
// Conv weight repack (validated R2).
// ===========================================================================
__global__ __launch_bounds__(256) void repack_kernel(
    const float* __restrict__ Wq,
    const float* __restrict__ Wk1, const float* __restrict__ Wk3,
    const float* __restrict__ Wk5, const float* __restrict__ Wk7,
    const float* __restrict__ Wv1, const float* __restrict__ Wv3,
    const float* __restrict__ Wv5, const float* __restrict__ Wv7,
    u16* __restrict__ wpack)
{
    int gid = blockIdx.x * 256 + threadIdx.x;
    int frag = gid >> 6, l = gid & 63;
    const float* W; int K, ocbase = 0, rel;
    if (frag < 1152) {
        W = Wq; K = 3; int slot = frag / 288; rel = frag % 288; ocbase = slot * 64;
    } else {
        int f = frag - 1152; int side = f / 2688; f %= 2688;
        if (f < 32)        { W = side ? Wv1 : Wk1; K = 1; rel = f; }
        else if (f < 320)  { W = side ? Wv3 : Wk3; K = 3; rel = f - 32; }
        else if (f < 1120) { W = side ? Wv5 : Wk5; K = 5; rel = f - 320; }
        else               { W = side ? Wv7 : Wk7; K = 7; rel = f - 1120; }
    }
    int og = rel & 3, cc = (rel >> 2) & 7, tap = rel >> 5;
    int dy = tap / K, dx = tap % K;
    int oc = ocbase + og * 16 + (l & 15);
    int c0 = cc * 32 + (l >> 4) * 8;
    u16 pk[8];
#pragma unroll
    for (int j = 0; j < 8; ++j)
        pk[j] = f2bf(W[((size_t)(oc * 256 + c0 + j) * K + dy) * K + dx]);
    *(int4*)&wpack[(size_t)frag * 512 + l * 8] = *(const int4*)pk;
}

// ===========================================================================
// FF/W repack. NOTE: launched AFTER reduce_kernel; w1p/w2p live in the
// dead wpack region (conv is done by then). Never overlaps live p5/p7.
// ===========================================================================
__global__ __launch_bounds__(256) void repack_ff_kernel(
    const float* __restrict__ W1, const float* __restrict__ W2,
    u16* __restrict__ w1p, u16* __restrict__ w2p)
{
    int gid = blockIdx.x * 256 + threadIdx.x;   // 192*256 = 49152
    int f = gid >> 6, l = gid & 63;
    u16 pk[8];
    if (f < 512) {
        int ks = f >> 5, nf = f & 31;
#pragma unroll
        for (int j = 0; j < 8; ++j)
            pk[j] = f2bf(W1[(size_t)(ks * 32 + (l >> 4) * 8 + j) * 512 + nf * 16 + (l & 15)]);
        *(int4*)&w1p[(size_t)f * 512 + l * 8] = *(const int4*)pk;
    } else {
        int f2 = f - 512;
        int ks = f2 >> 4, nf = f2 & 15;
#pragma unroll
        for (int j = 0; j < 8; ++j)
            pk[j] = f2bf(W2[(size_t)(ks * 32 + (l >> 4) * 8 + j) * 256 + nf * 16 + (l & 15)]);
        *(int4*)&w2p[(size_t)f2 * 512 + l * 8] = *(const int4*)pk;
    }
}

// ===========================================================================
// MFMA implicit-GEMM conv (validated R2).
// ===========================================================================
template<int K>
DEV void conv_mfma_body(const float* __restrict__ srcp,
                        const u16* __restrict__ wsec,
                        float* __restrict__ dst,
                        u16* Bt, int y0, int cch0, int ncc, int t)
{
    constexpr int P = K / 2;
    const int w = t >> 6, l = t & 63;
    const int chi = l >> 4, ln = l & 15;
    const int rowbase = chi * 14 + w * 2 + 3 - P;
    const int colbase = ln + 3 - P;
    f32x4 acc[4][4];
#pragma unroll
    for (int m = 0; m < 4; ++m)
#pragma unroll
        for (int n = 0; n < 4; ++n) acc[m][n] = (f32x4){0.f, 0.f, 0.f, 0.f};

    for (int cc = 0; cc < ncc; ++cc) {
        const int ccg = cch0 + cc;
        const int cg0 = ccg * 32;
        __syncthreads();
        for (int u = 0; u < 9; ++u) {
            int unit = t + (u << 8);
            if (unit < 1792) {
                int xv = unit & 31, r = unit >> 5;
                int yy = r % 14, ch = r / 14;
                int ygl = y0 - 3 + yy;
                u16 pk[8];
                if ((unsigned)ygl < 32u) {
                    const float* sp = srcp + (size_t)(cg0 + ch * 8) * 1024 + ygl * 32 + xv;
#pragma unroll
                    for (int j = 0; j < 8; ++j) pk[j] = f2bf(sp[j * 1024]);
                } else {
#pragma unroll
                    for (int j = 0; j < 8; ++j) pk[j] = 0;
                }
                *(int4*)&Bt[((ch * 14 + yy) * 40 + xv + 3) * 8] = *(const int4*)pk;
            } else if (unit < 2240) {
                int hu = unit - 1792;
                int hx = hu & 7; int xi = hx < 3 ? hx : hx + 32;
                int r = hu >> 3; int yy = r % 14, ch = r / 14;
                int4 z = {0, 0, 0, 0};
                *(int4*)&Bt[((ch * 14 + yy) * 40 + xi) * 8] = z;
            }
        }
        __syncthreads();
        for (int dy = 0; dy < K; ++dy) {
#pragma unroll
            for (int dx = 0; dx < K; ++dx) {
                const int tap = dy * K + dx;
                const u16* wp = wsec + ((size_t)(tap * 8 + ccg) * 4) * 512 + l * 8;
                bf16x8 a0 = *(const bf16x8*)(wp);
                bf16x8 a1 = *(const bf16x8*)(wp + 512);
                bf16x8 a2 = *(const bf16x8*)(wp + 1024);
                bf16x8 a3 = *(const bf16x8*)(wp + 1536);
                bf16x8 bf[4];
#pragma unroll
                for (int n = 0; n < 4; ++n) {
                    int row = rowbase + dy + (n >> 1);
                    int col = colbase + dx + (n & 1) * 16;
                    bf[n] = *(const bf16x8*)&Bt[(row * 40 + col) * 8];
                }
#pragma unroll
                for (int n = 0; n < 4; ++n) {
                    acc[0][n] = __builtin_amdgcn_mfma_f32_16x16x32_bf16(a0, bf[n], acc[0][n], 0, 0, 0);
                    acc[1][n] = __builtin_amdgcn_mfma_f32_16x16x32_bf16(a1, bf[n], acc[1][n], 0, 0, 0);
                    acc[2][n] = __builtin_amdgcn_mfma_f32_16x16x32_bf16(a2, bf[n], acc[2][n], 0, 0, 0);
                    acc[3][n] = __builtin_amdgcn_mfma_f32_16x16x32_bf16(a3, bf[n], acc[3][n], 0, 0, 0);
                }
            }
        }
    }
#pragma unroll
    for (int m = 0; m < 4; ++m)
#pragma unroll
        for (int n = 0; n < 4; ++n) {
            int y = y0 + w * 2 + (n >> 1);
            int px = y * 32 + (n & 1) * 16 + ln;
            int ocb = m * 16 + chi * 4;
#pragma unroll
            for (int r = 0; r < 4; ++r)
                dst[(size_t)(ocb + r) * 1024 + px] = acc[m][n][r];
        }
}

__global__ __launch_bounds__(256) void conv_mfma_kernel(
    const float* __restrict__ x, const float* __restrict__ source,
    const u16* __restrict__ wpack,
    float* __restrict__ qb, float* __restrict__ kb, float* __restrict__ vb,
    float* __restrict__ p5, float* __restrict__ p7)
{
    __shared__ u16 Bt[4 * 14 * 40 * 8];
    const int bx = blockIdx.x, t = threadIdx.x;
    const int b = bx / 80, r = bx % 80;
    if (r < 16) {
        int slot = r >> 2, yt = r & 3;
        conv_mfma_body<3>(x + (size_t)b * 262144,
                          wpack + (size_t)(slot * 288) * 512,
                          qb + ((size_t)b * 256 + slot * 64) * 1024,
                          Bt, yt * 8, 0, 8, t);
        return;
    }
    const int r2 = r - 16, side = r2 >> 5, r3 = r2 & 31;
    const float* sp = source + (size_t)b * 262144;
    float* fin = side ? vb : kb;
    const size_t wkb = 1152 + (size_t)side * 2688;
    if (r3 < 4) {
        conv_mfma_body<1>(sp, wpack + (wkb + 0) * 512,
                          fin + ((size_t)b * 256) * 1024, Bt, r3 * 8, 0, 8, t);
    } else if (r3 < 8) {
        conv_mfma_body<3>(sp, wpack + (wkb + 32) * 512,
                          fin + ((size_t)b * 256 + 64) * 1024, Bt, (r3 - 4) * 8, 0, 8, t);
    } else if (r3 < 16) {
        int t5 = r3 - 8, cpart = t5 >> 2, yt = t5 & 3;
        conv_mfma_body<5>(sp, wpack + (wkb + 320) * 512,
                          p5 + (((size_t)side * 2 + cpart) * 8 + b) * 65536,
                          Bt, yt * 8, cpart * 4, 4, t);
    } else {
        int t7 = r3 - 16, cpart = t7 >> 2, yt = t7 & 3;
        conv_mfma_body<7>(sp, wpack + (wkb + 1120) * 512,
                          p7 + (((size_t)side * 4 + cpart) * 8 + b) * 65536,
                          Bt, yt * 8, cpart * 2, 2, t);
    }
}

__global__ __launch_bounds__(256) void reduce_kernel(
    const float* __restrict__ p5, const float* __restrict__ p7,
    float* __restrict__ kb, float* __restrict__ vb)
{
    int gid = blockIdx.x * 256 + threadIdx.x;
    int px4 = gid & 255;
    int rr = gid >> 8;
    int oc = rr & 127, b = (rr >> 7) & 7, side = rr >> 10;
    float* outb = side ? vb : kb;
    if (oc < 64) {
        const float4* a0 = (const float4*)(p5 + (((size_t)side * 2 + 0) * 8 + b) * 65536 + (size_t)oc * 1024) + px4;
        const float4* a1 = (const float4*)(p5 + (((size_t)side * 2 + 1) * 8 + b) * 65536 + (size_t)oc * 1024) + px4;
        float4 u = *a0, v = *a1;
        float4 s = make_float4(u.x + v.x, u.y + v.y, u.z + v.z, u.w + v.w);
        *((float4*)(outb + ((size_t)b * 256 + 128 + oc) * 1024) + px4) = s;
    } else {
        int o7 = oc - 64;
        float4 s = make_float4(0.f, 0.f, 0.f, 0.f);
#pragma unroll
        for (int p = 0; p < 4; ++p) {
            float4 u = *((const float4*)(p7 + (((size_t)side * 4 + p) * 8 + b) * 65536 + (size_t)o7 * 1024) + px4);
            s.x += u.x; s.y += u.y; s.z += u.z; s.w += u.w;
        }
        *((float4*)(outb + ((size_t)b * 256 + 192 + o7) * 1024) + px4) = s;
    }
}

// ===========================================================================
// Fused QK^T + softmax -> vis.
// ===========================================================================
__global__ __launch_bounds__(512) void qk_sm_kernel(const float* __restrict__ q,
                                                    const float* __restrict__ k,
                                                    float* __restrict__ vis)
{
    __shared__ u16 kf[32 * 512];
    __shared__ u16 qf[4 * 512];
    __shared__ float redM[32 * 8];
    __shared__ float redS[32 * 8];
    const int t = threadIdx.x;
    const int bx = blockIdx.x;          // 8b*4h*32lt = 1024
    const int b = bx >> 7, h = (bx >> 5) & 3, l0 = (bx & 31) * 32;
    const float* qp = q + ((size_t)b * 256 + h * 64) * 1024;
    const float* kp = k + ((size_t)b * 256 + h * 64) * 1024;

    if (t < 256) {
        int r = t & 31, dblk = t >> 5;
        u16 pk[8];
#pragma unroll
        for (int j = 0; j < 8; ++j)
            pk[j] = f2bf(qp[(size_t)(dblk * 8 + j) * 1024 + l0 + r]);
        *(int4*)&qf[(((r >> 4) * 2 + (dblk >> 2)) * 64 + (dblk & 3) * 16 + (r & 15)) * 8] = *(const int4*)pk;
    }
    __syncthreads();

    const int w = t >> 6, l = t & 63, ln = l & 15, lg = l >> 4;
    bf16x8 a[2][2];
#pragma unroll
    for (int fr = 0; fr < 2; ++fr)
#pragma unroll
        for (int ks = 0; ks < 2; ++ks)
            a[fr][ks] = *(const bf16x8*)&qf[((fr * 2 + ks) * 64 + l) * 8];

    f32x4 acc[2][4][2];
#pragma unroll
    for (int fr = 0; fr < 2; ++fr)
#pragma unroll
        for (int cc = 0; cc < 4; ++cc)
#pragma unroll
            for (int f = 0; f < 2; ++f) acc[fr][cc][f] = (f32x4){0.f, 0.f, 0.f, 0.f};

#pragma unroll
    for (int cc = 0; cc < 4; ++cc) {
        __syncthreads();
#pragma unroll
        for (int it = 0; it < 4; ++it) {
            int unit = it * 512 + t;
            int sl = unit & 255, dblk = unit >> 8;
            u16 pk[8];
            const float* kpp = kp + (size_t)(dblk * 8) * 1024 + cc * 256 + sl;
#pragma unroll
            for (int j = 0; j < 8; ++j) pk[j] = f2bf(kpp[j * 1024]);
            *(int4*)&kf[(((sl >> 4) * 2 + (dblk >> 2)) * 64 + (dblk & 3) * 16 + (sl & 15)) * 8] = *(const int4*)pk;
        }
        __syncthreads();
#pragma unroll
        for (int f = 0; f < 2; ++f) {
            int fg = (w * 2 + f) * 2;
            bf16x8 b0 = *(const bf16x8*)&kf[((fg + 0) * 64 + l) * 8];
            bf16x8 b1 = *(const bf16x8*)&kf[((fg + 1) * 64 + l) * 8];
#pragma unroll
            for (int fr = 0; fr < 2; ++fr) {
                acc[fr][cc][f] = __builtin_amdgcn_mfma_f32_16x16x32_bf16(a[fr][0], b0, acc[fr][cc][f], 0, 0, 0);
                acc[fr][cc][f] = __builtin_amdgcn_mfma_f32_16x16x32_bf16(a[fr][1], b1, acc[fr][cc][f], 0, 0, 0);
            }
        }
    }

#pragma unroll
    for (int fr = 0; fr < 2; ++fr)
#pragma unroll
        for (int cc = 0; cc < 4; ++cc)
#pragma unroll
            for (int f = 0; f < 2; ++f)
#pragma unroll
                for (int e = 0; e < 4; ++e) acc[fr][cc][f][e] *= 0.125f;

    float rmax[2][4];
#pragma unroll
    for (int fr = 0; fr < 2; ++fr)
#pragma unroll
        for (int reg = 0; reg < 4; ++reg) {
            float m = -1e30f;
#pragma unroll
            for (int cc = 0; cc < 4; ++cc)
#pragma unroll
                for (int f = 0; f < 2; ++f) m = fmaxf(m, acc[fr][cc][f][reg]);
#pragma unroll
            for (int off = 1; off < 16; off <<= 1) m = fmaxf(m, __shfl_xor(m, off));
            if (ln == 0) redM[(fr * 16 + lg * 4 + reg) * 8 + w] = m;
            rmax[fr][reg] = m;
        }
    __syncthreads();
#pragma unroll
    for (int fr = 0; fr < 2; ++fr)
#pragma unroll
        for (int reg = 0; reg < 4; ++reg) {
            int r = fr * 16 + lg * 4 + reg;
            float m = redM[r * 8];
#pragma unroll
            for (int ww = 1; ww < 8; ++ww) m = fmaxf(m, redM[r * 8 + ww]);
            rmax[fr][reg] = m;
        }
#pragma unroll
    for (int fr = 0; fr < 2; ++fr)
#pragma unroll
        for (int reg = 0; reg < 4; ++reg) {
            float s = 0.f;
            float m = rmax[fr][reg];
#pragma unroll
            for (int cc = 0; cc < 4; ++cc)
#pragma unroll
                for (int f = 0; f < 2; ++f) {
                    float e = __expf(acc[fr][cc][f][reg] - m);
                    acc[fr][cc][f][reg] = e;
                    s += e;
                }
#pragma unroll
            for (int off = 1; off < 16; off <<= 1) s += __shfl_xor(s, off);
            if (ln == 0) redS[(fr * 16 + lg * 4 + reg) * 8 + w] = s;
        }
    __syncthreads();
    float* visp = vis + (((size_t)(b * 4 + h)) << 20);
#pragma unroll
    for (int fr = 0; fr < 2; ++fr)
#pragma unroll
        for (int reg = 0; reg < 4; ++reg) {
            int r = fr * 16 + lg * 4 + reg;
            float s = redS[r * 8] + redS[r * 8 + 1] + redS[r * 8 + 2] + redS[r * 8 + 3]
                    + redS[r * 8 + 4] + redS[r * 8 + 5] + redS[r * 8 + 6] + redS[r * 8 + 7];
            float inv = 1.f / s;
            float* vr = visp + (size_t)(l0 + r) * 1024 + w * 32 + ln;
#pragma unroll
            for (int cc = 0; cc < 4; ++cc)
#pragma unroll
                for (int f = 0; f < 2; ++f)
                    vr[cc * 256 + f * 16] = acc[fr][cc][f][reg] * inv;
        }
}

// ---------------------------------------------------------------------------
// Linear attention (validated R2).
// ---------------------------------------------------------------------------
__global__ __launch_bounds__(256) void kv_kernel(const float* __restrict__ k,
                                                 const float* __restrict__ v,
                                                 float* __restrict__ KVp,
                                                 float* __restrict__ Ksump)
{
    __shared__ float4 Kt4[64*17];
    __shared__ float4 Vt4[64*16];
    float* Kt = (float*)Kt4;
    float* Vt = (float*)Vt4;
    const int t = threadIdx.x;
    const int bx = blockIdx.x;
    const int b = bx >> 4, h = (bx >> 2) & 3, ch = bx & 3;
    const float* kb = k + ((size_t)b*256 + h*64)*1024 + ch*256;
    const float* vb = v + ((size_t)b*256 + h*64)*1024 + ch*256;
    const int d = t >> 2, v0 = (t & 3) * 16;
    float4 acc[4];
#pragma unroll
    for (int j = 0; j < 4; ++j) acc[j] = make_float4(0.f, 0.f, 0.f, 0.f);
    float ks = 0.f;
    for (int st = 0; st < 4; ++st) {
        __syncthreads();
        {
            int dd = t >> 2, r0 = (t & 3) * 16;
#pragma unroll
            for (int mm = 0; mm < 4; ++mm) {
                float4 kv = *(const float4*)(kb + dd*1024 + st*64 + r0 + mm*4);
                Kt[(r0+mm*4+0)*68 + dd] = elu1(kv.x);
                Kt[(r0+mm*4+1)*68 + dd] = elu1(kv.y);
                Kt[(r0+mm*4+2)*68 + dd] = elu1(kv.z);
                Kt[(r0+mm*4+3)*68 + dd] = elu1(kv.w);
                float4 vv = *(const float4*)(vb + dd*1024 + st*64 + r0 + mm*4);
                Vt[(r0+mm*4+0)*64 + dd] = vv.x;
                Vt[(r0+mm*4+1)*64 + dd] = vv.y;
                Vt[(r0+mm*4+2)*64 + dd] = vv.z;
                Vt[(r0+mm*4+3)*64 + dd] = vv.w;
            }
        }
        __syncthreads();
#pragma unroll 8
        for (int s = 0; s < 64; ++s) {
            float kf = Kt[s*68 + d];
            const float4* vp = (const float4*)(Vt + s*64 + v0);
#pragma unroll
            for (int j = 0; j < 4; ++j) {
                float4 vv = vp[j];
                acc[j].x += kf*vv.x; acc[j].y += kf*vv.y;
                acc[j].z += kf*vv.z; acc[j].w += kf*vv.w;
            }
        }
        if (t < 64) {
#pragma unroll 8
            for (int s = 0; s < 64; ++s) ks += Kt[s*68 + t];
        }
    }
    float* op = KVp + ((size_t)((ch*32 + b*4 + h)*64 + d))*64 + v0;
#pragma unroll
    for (int j = 0; j < 4; ++j) ((float4*)op)[j] = acc[j];
    if (t < 64) Ksump[(size_t)(ch*32 + b*4 + h)*64 + t] = ks;
}

__global__ __launch_bounds__(256) void msg_kernel(const float* __restrict__ q,
                                                  const float* __restrict__ KVp,
                                                  const float* __restrict__ Ksump,
                                                  float* __restrict__ msg)
{
    __shared__ float4 kvl4[4*1028];
    __shared__ float ksl[4*65];
    float* kvl = (float*)kvl4;
    const int t = threadIdx.x;
    const int bx = blockIdx.x;
    const int b = bx >> 4;
    const int l0 = (bx & 15) * 64;
    for (int m = 0; m < 64; ++m) {
        int idx = t + 256*m;
        int hh = idx >> 12, dd = (idx >> 6) & 63, vv = idx & 63;
        float s = 0.f;
#pragma unroll
        for (int ch = 0; ch < 4; ++ch)
            s += KVp[(size_t)((ch*32 + b*4))*4096 + idx];
        kvl[hh*4112 + dd*64 + vv] = s;
    }
    {
        float s = 0.f;
#pragma unroll
        for (int ch = 0; ch < 4; ++ch)
            s += Ksump[(size_t)(ch*32 + b*4)*64 + t];
        ksl[(t >> 6)*65 + (t & 63)] = s;
    }
    __syncthreads();
    const int h = t & 3, l = l0 + (t >> 2);
    const float* qb = q + ((size_t)b*256 + h*64)*1024 + l;
    float qf[64];
#pragma unroll
    for (int dd = 0; dd < 64; ++dd) qf[dd] = elu1(qb[dd*1024]);
    float zd = 1e-6f;
#pragma unroll
    for (int dd = 0; dd < 64; ++dd) zd += qf[dd] * ksl[h*65 + dd];
    const float Z = 1.f / zd;
    float* op = msg + ((size_t)(b*1024 + l))*256 + h*64;
    for (int c0 = 0; c0 < 64; c0 += 16) {
        float4 a[4];
#pragma unroll
        for (int j = 0; j < 4; ++j) a[j] = make_float4(0.f, 0.f, 0.f, 0.f);
#pragma unroll
        for (int dd = 0; dd < 64; ++dd) {
            float qv = qf[dd];
            const float4* kp = (const float4*)(kvl + h*4112 + dd*64 + c0);
#pragma unroll
            for (int j = 0; j < 4; ++j) {
                float4 kk = kp[j];
                a[j].x += qv*kk.x; a[j].y += qv*kk.y;
                a[j].z += qv*kk.z; a[j].w += qv*kk.w;
            }
        }
#pragma unroll
        for (int j = 0; j < 4; ++j) {
            a[j].x *= Z; a[j].y *= Z; a[j].z *= Z; a[j].w *= Z;
            ((float4*)(op + c0))[j] = a[j];
        }
    }
}

__global__ __launch_bounds__(256) void merge_ln1_kernel(const float* __restrict__ msg,
                                                        const float* __restrict__ Wm,
                                                        const float* __restrict__ g1,
                                                        const float* __restrict__ b1,
                                                        float* __restrict__ msgm)
{
    __shared__ float4 mL4[16*65];
    __shared__ float mv[32];
    float* mL = (float*)mL4;
    const int t = threadIdx.x;
    const size_t base = (size_t)blockIdx.x * 16;
    {
        int r = t >> 4, cb = t & 15;
#pragma unroll
        for (int j = 0; j < 16; ++j)
            mL[r*260 + cb + 16*j] = msg[(base + r)*256 + cb + 16*j];
    }
    __syncthreads();
    float acc[16];
#pragma unroll
    for (int r = 0; r < 16; ++r) acc[r] = 0.f;
    for (int i = 0; i < 256; i += 4) {
        float w0 = Wm[(size_t)(i+0)*256 + t];
        float w1 = Wm[(size_t)(i+1)*256 + t];
        float w2 = Wm[(size_t)(i+2)*256 + t];
        float w3 = Wm[(size_t)(i+3)*256 + t];
#pragma unroll
        for (int r = 0; r < 16; ++r) {
            float4 m4 = mL4[r*65 + (i >> 2)];
            acc[r] += m4.x*w0 + m4.y*w1 + m4.z*w2 + m4.w*w3;
        }
    }
    __syncthreads();
#pragma unroll
    for (int r = 0; r < 16; ++r) mL[r*260 + t] = acc[r];
    __syncthreads();
    {
        int wid = t >> 6, lane = t & 63;
#pragma unroll
        for (int rr = 0; rr < 4; ++rr) {
            int r = wid*4 + rr;
            float s1 = 0.f, s2 = 0.f;
#pragma unroll
            for (int m = 0; m < 4; ++m) {
                float vv = mL[r*260 + lane + 64*m];
                s1 += vv; s2 += vv*vv;
            }
#pragma unroll
            for (int off = 1; off < 64; off <<= 1) {
                s1 += __shfl_xor(s1, off);
                s2 += __shfl_xor(s2, off);
            }
            if (lane == 0) {
                float mean = s1 * (1.f/256.f);
                float var  = s2 * (1.f/256.f) - mean*mean;
                mv[r*2]   = mean;
                mv[r*2+1] = rsqrtf(var + 1e-5f);
            }
        }
    }
    __syncthreads();
    const float gg = g1[t], bb = b1[t];
#pragma unroll
    for (int r = 0; r < 16; ++r) {
        float val = (mL[r*260 + t] - mv[r*2]) * mv[r*2+1] * gg + bb;
        msgm[(base + r)*256 + t] = val;
    }
}

// ===========================================================================
// FF via MFMA (as R3; bug was workspace overlap, not this kernel).
// ===========================================================================
__global__ __launch_bounds__(256) void ff_mfma_kernel(
    const float* __restrict__ x, const float* __restrict__ msgm,
    const u16* __restrict__ w1p, const u16* __restrict__ w2p,
    const float* __restrict__ g2, const float* __restrict__ b2,
    float* __restrict__ out)
{
    __shared__ u16 tile[32 * 520];
    __shared__ float redS[32 * 4];
    __shared__ float redQ[32 * 4];
    float* tf = (float*)tile;
    const int t = threadIdx.x;
    const int base = blockIdx.x * 32;       // 256 blocks
    const int b = base >> 10, l0 = base & 1023;
    const int w = t >> 6, l = t & 63, ln = l & 15, lg = l >> 4;

    {
        int rr = t & 31, cg = t >> 5;
        for (int cci = 0; cci < 32; ++cci) {
            int c = cci * 8 + cg;
            float v = x[((size_t)b * 256 + c) * 1024 + l0 + rr];
            tile[rr * 520 + c] = f2bf(v);
        }
        int r = t >> 3, cb = (t & 7) * 32;
#pragma unroll
        for (int i = 0; i < 8; ++i) {
            float4 v = *(const float4*)&msgm[((size_t)(base + r)) * 256 + cb + i * 4];
            u32 p0 = (u32)f2bf(v.x) | ((u32)f2bf(v.y) << 16);
            u32 p1 = (u32)f2bf(v.z) | ((u32)f2bf(v.w) << 16);
            *(u32*)&tile[r * 520 + 256 + cb + i * 4] = p0;
            *(u32*)&tile[r * 520 + 256 + cb + i * 4 + 2] = p1;
        }
    }
    __syncthreads();

    f32x4 acc[2][8];
#pragma unroll
    for (int fr = 0; fr < 2; ++fr)
#pragma unroll
        for (int fc = 0; fc < 8; ++fc) acc[fr][fc] = (f32x4){0.f, 0.f, 0.f, 0.f};
    for (int ks = 0; ks < 16; ++ks) {
        bf16x8 a0 = *(const bf16x8*)&tile[(ln) * 520 + ks * 32 + lg * 8];
        bf16x8 a1 = *(const bf16x8*)&tile[(16 + ln) * 520 + ks * 32 + lg * 8];
#pragma unroll
        for (int fc = 0; fc < 8; ++fc) {
            bf16x8 bb = *(const bf16x8*)&w1p[((size_t)(ks * 32 + w * 8 + fc) * 64 + l) * 8];
            acc[0][fc] = __builtin_amdgcn_mfma_f32_16x16x32_bf16(a0, bb, acc[0][fc], 0, 0, 0);
            acc[1][fc] = __builtin_amdgcn_mfma_f32_16x16x32_bf16(a1, bb, acc[1][fc], 0, 0, 0);
        }
    }
    __syncthreads();
#pragma unroll
    for (int fr = 0; fr < 2; ++fr)
#pragma unroll
        for (int fc = 0; fc < 8; ++fc)
#pragma unroll
            for (int reg = 0; reg < 4; ++reg) {
                int r = fr * 16 + lg * 4 + reg;
                int c = w * 128 + fc * 16 + ln;
                tile[r * 520 + c] = f2bf(fmaxf(acc[fr][fc][reg], 0.f));
            }
    __syncthreads();

    f32x4 acc2[2][4];
#pragma unroll
    for (int fr = 0; fr < 2; ++fr)
#pragma unroll
        for (int fc = 0; fc < 4; ++fc) acc2[fr][fc] = (f32x4){0.f, 0.f, 0.f, 0.f};
    for (int ks = 0; ks < 16; ++ks) {
        bf16x8 a0 = *(const bf16x8*)&tile[(ln) * 520 + ks * 32 + lg * 8];
        bf16x8 a1 = *(const bf16x8*)&tile[(16 + ln) * 520 + ks * 32 + lg * 8];
#pragma unroll
        for (int fc = 0; fc < 4; ++fc) {
            bf16x8 bb = *(const bf16x8*)&w2p[((size_t)(ks * 16 + w * 4 + fc) * 64 + l) * 8];
            acc2[0][fc] = __builtin_amdgcn_mfma_f32_16x16x32_bf16(a0, bb, acc2[0][fc], 0, 0, 0);
            acc2[1][fc] = __builtin_amdgcn_mfma_f32_16x16x32_bf16(a1, bb, acc2[1][fc], 0, 0, 0);
        }
    }
#pragma unroll
    for (int fr = 0; fr < 2; ++fr)
#pragma unroll
        for (int reg = 0; reg < 4; ++reg) {
            float s = 0.f, qsum = 0.f;
#pragma unroll
            for (int fc = 0; fc < 4; ++fc) {
                float v = acc2[fr][fc][reg];
                s += v; qsum += v * v;
            }
#pragma unroll
            for (int off = 1; off < 16; off <<= 1) {
                s += __shfl_xor(s, off);
                qsum += __shfl_xor(qsum, off);
            }
            if (ln == 0) {
                int r = fr * 16 + lg * 4 + reg;
                redS[r * 4 + w] = s;
                redQ[r * 4 + w] = qsum;
            }
        }
    __syncthreads();
    float mean[2][4], rstd[2][4];
#pragma unroll
    for (int fr = 0; fr < 2; ++fr)
#pragma unroll
        for (int reg = 0; reg < 4; ++reg) {
            int r = fr * 16 + lg * 4 + reg;
            float s = redS[r * 4] + redS[r * 4 + 1] + redS[r * 4 + 2] + redS[r * 4 + 3];
            float qs = redQ[r * 4] + redQ[r * 4 + 1] + redQ[r * 4 + 2] + redQ[r * 4 + 3];
            float m = s * (1.f / 256.f);
            mean[fr][reg] = m;
            rstd[fr][reg] = rsqrtf(qs * (1.f / 256.f) - m * m + 1e-5f);
        }
#pragma unroll
    for (int fc = 0; fc < 4; ++fc) {
        int c = w * 64 + fc * 16 + ln;
        float gg = g2[c], bb = b2[c];
#pragma unroll
        for (int fr = 0; fr < 2; ++fr)
#pragma unroll
            for (int reg = 0; reg < 4; ++reg) {
                int r = fr * 16 + lg * 4 + reg;
                tf[r * 260 + c] = (acc2[fr][fc][reg] - mean[fr][reg]) * rstd[fr][reg] * gg + bb;
            }
    }
    __syncthreads();
    {
        const float* xp = x + ((size_t)b * 256 + t) * 1024 + l0;
        float* op = out + ((size_t)b * 256 + t) * 1024 + l0;
#pragma unroll
        for (int i = 0; i < 8; ++i) {
            float4 xv = *(const float4*)(xp + i * 4);
            float4 o;
            o.x = xv.x + tf[(i * 4 + 0) * 260 + t];
            o.y = xv.y + tf[(i * 4 + 1) * 260 + t];
            o.z = xv.z + tf[(i * 4 + 2) * 260 + t];
            o.w = xv.w + tf[(i * 4 + 3) * 260 + t];
            *(float4*)(op + i * 4) = o;
        }
    }
}

// ---------------------------------------------------------------------------
extern "C" void kernel_launch(void* const* d_in, const int* in_sizes, int n_in,
                              void* d_out, int out_size, void* d_ws, size_t ws_size,
                              hipStream_t stream)
{
    const float* x    = (const float*)d_in[0];
    const float* src  = (const float*)d_in[1];
    const float* Wq   = (const float*)d_in[2];
    const float* Wk1  = (const float*)d_in[3];
    const float* Wk3  = (const float*)d_in[4];
    const float* Wk5  = (const float*)d_in[5];
    const float* Wk7  = (const float*)d_in[6];
    const float* Wv1  = (const float*)d_in[7];
    const float* Wv3  = (const float*)d_in[8];
    const float* Wv5  = (const float*)d_in[9];
    const float* Wv7  = (const float*)d_in[10];
    const float* Wm   = (const float*)d_in[11];
    const float* g1   = (const float*)d_in[12];
    const float* b1   = (const float*)d_in[13];
    const float* g2   = (const float*)d_in[14];
    const float* b2   = (const float*)d_in[15];
    const float* W1   = (const float*)d_in[16];
    const float* W2   = (const float*)d_in[17];

    float* out = (float*)d_out;
    float* vis = out + 2097152;          // [b,h,l,s]

    // Workspace lifetime map (floats):
    //   [0,        2097152) qb            live conv..msg
    //   [2097152,  4194304) kb            live conv..kv
    //   [4194304,  6291456) vb            live conv..kv
    //   [6291456,  7962624) wpack         live repack..conv; THEN w1p/w2p
    //   [7962624, 10059776) p5            live conv..reduce; THEN msg
    //   [10059776,14254080) p7            live conv..reduce; THEN msgm/KVp/Ksump
    u16*   wpack = (u16*)((float*)d_ws + 6291456);
    float* ws    = (float*)d_ws;
    float* qb    = ws;
    float* kb    = ws + 2097152;
    float* vb    = ws + 4194304;
    float* p5    = ws + 7962624;
    float* p7    = ws + 10059776;
    float* msg   = ws + 7962624;         // alias p5 (dead after reduce)
    float* msgm  = ws + 10059776;        // alias p7 (dead after reduce)
    float* KVp   = ws + 12156928;        // alias inside p7 (dead after reduce)
    float* Ksump = ws + 12681216;
    u16*   w1p   = (u16*)(ws + 6291456); // alias wpack (dead after conv)
    u16*   w2p   = (u16*)(ws + 6422528);

    repack_kernel   <<<1632, 256, 0, stream>>>(Wq, Wk1, Wk3, Wk5, Wk7,
                                               Wv1, Wv3, Wv5, Wv7, wpack);
    conv_mfma_kernel<<<640,  256, 0, stream>>>(x, src, wpack, qb, kb, vb, p5, p7);
    reduce_kernel   <<<2048, 256, 0, stream>>>(p5, p7, kb, vb);
    repack_ff_kernel<<<192,  256, 0, stream>>>(W1, W2, w1p, w2p);
    qk_sm_kernel    <<<1024, 512, 0, stream>>>(qb, kb, vis);
    kv_kernel       <<<128,  256, 0, stream>>>(kb, vb, KVp, Ksump);
    msg_kernel      <<<128,  256, 0, stream>>>(qb, KVp, Ksump, msg);
    merge_ln1_kernel<<<512,  256, 0, stream>>>(msg, Wm, g1, b1, msgm);
    ff_mfma_kernel  <<<256,  256, 0, stream>>>(x, msgm, w1p, w2p, g2, b2, out);
}

// Round 6
// 311.567 us; speedup vs baseline: 11.3214x; 1.1355x over previous
//
#include <hip/hip_runtime.h>

#define DEV __device__ __forceinline__

typedef unsigned short u16;
typedef unsigned int u32;
typedef __bf16 bf16x8 __attribute__((ext_vector_type(8)));
typedef float f32x4 __attribute__((ext_vector_type(4)));

DEV float elu1(float x) { return x > 0.f ? x + 1.f : __expf(x); }

DEV u16 f2bf(float f) {
    union { float f; unsigned u; } v; v.f = f;
    unsigned r = v.u + 0x7fffu + ((v.u >> 16) & 1u);
    return (u16)(r >> 16);
}

// ===========================================================================
// Conv weight repack (validated R2).
// ===========================================================================
__global__ __launch_bounds__(256) void repack_kernel(
    const float* __restrict__ Wq,
    const float* __restrict__ Wk1, const float* __restrict__ Wk3,
    const float* __restrict__ Wk5, const float* __restrict__ Wk7,
    const float* __restrict__ Wv1, const float* __restrict__ Wv3,
    const float* __restrict__ Wv5, const float* __restrict__ Wv7,
    u16* __restrict__ wpack)
{
    int gid = blockIdx.x * 256 + threadIdx.x;
    int frag = gid >> 6, l = gid & 63;
    const float* W; int K, ocbase = 0, rel;
    if (frag < 1152) {
        W = Wq; K = 3; int slot = frag / 288; rel = frag % 288; ocbase = slot * 64;
    } else {
        int f = frag - 1152; int side = f / 2688; f %= 2688;
        if (f < 32)        { W = side ? Wv1 : Wk1; K = 1; rel = f; }
        else if (f < 320)  { W = side ? Wv3 : Wk3; K = 3; rel = f - 32; }
        else if (f < 1120) { W = side ? Wv5 : Wk5; K = 5; rel = f - 320; }
        else               { W = side ? Wv7 : Wk7; K = 7; rel = f - 1120; }
    }
    int og = rel & 3, cc = (rel >> 2) & 7, tap = rel >> 5;
    int dy = tap / K, dx = tap % K;
    int oc = ocbase + og * 16 + (l & 15);
    int c0 = cc * 32 + (l >> 4) * 8;
    u16 pk[8];
#pragma unroll
    for (int j = 0; j < 8; ++j)
        pk[j] = f2bf(W[((size_t)(oc * 256 + c0 + j) * K + dy) * K + dx]);
    *(int4*)&wpack[(size_t)frag * 512 + l * 8] = *(const int4*)pk;
}

// ===========================================================================
// cast_src: fp32 NCHW -> bf16 blocked [b][cc8][pix1024][c32] for x and source.
// ===========================================================================
__global__ __launch_bounds__(256) void cast_src_kernel(
    const float* __restrict__ x, const float* __restrict__ src,
    u16* __restrict__ xbh, u16* __restrict__ sbh)
{
    __shared__ float lds[32 * 129];
    const int i = blockIdx.x, t = threadIdx.x;   // 1024 blocks
    const int inp = i >> 9, rem = i & 511;
    const int b = rem >> 6, cc = (rem >> 3) & 7, pxb = rem & 7;
    const float* in = (inp ? src : x) + ((size_t)b * 256 + cc * 32) * 1024 + pxb * 128;
    u16* outp = (inp ? sbh : xbh) + (size_t)b * 262144 + (size_t)cc * 32768 + pxb * 128 * 32;
#pragma unroll
    for (int u = 0; u < 4; ++u) {
        int unit = t + u * 256;
        int r = unit >> 5, px4 = unit & 31;
        float4 v = *(const float4*)(in + (size_t)r * 1024 + px4 * 4);
        lds[r * 129 + px4 * 4 + 0] = v.x;
        lds[r * 129 + px4 * 4 + 1] = v.y;
        lds[r * 129 + px4 * 4 + 2] = v.z;
        lds[r * 129 + px4 * 4 + 3] = v.w;
    }
    __syncthreads();
#pragma unroll
    for (int u = 0; u < 2; ++u) {
        int unit = t + u * 256;
        int px = unit >> 2, cg = unit & 3;
        u16 pk[8];
#pragma unroll
        for (int j = 0; j < 8; ++j) pk[j] = f2bf(lds[(cg * 8 + j) * 129 + px]);
        *(int4*)&outp[px * 32 + cg * 8] = *(const int4*)pk;
    }
}

// ===========================================================================
// cast_qk: qb/kb fp32 [b][c][l] -> bf16 [b*4+h][l][64] for qk_sm staging.
// ===========================================================================
__global__ __launch_bounds__(256) void cast_qk_kernel(
    const float* __restrict__ qb, const float* __restrict__ kb,
    u16* __restrict__ qbt, u16* __restrict__ kbt)
{
    __shared__ float lds[64 * 65];
    const int i = blockIdx.x, t = threadIdx.x;   // 1024 blocks
    const int inp = i >> 9, rem = i & 511;
    const int b = rem >> 6, h = (rem >> 4) & 3, pxb = rem & 15;
    const float* in = (inp ? kb : qb) + ((size_t)b * 256 + h * 64) * 1024 + pxb * 64;
    u16* outp = (inp ? kbt : qbt) + (((size_t)(b * 4 + h)) * 1024 + pxb * 64) * 64;
#pragma unroll
    for (int u = 0; u < 4; ++u) {
        int unit = t + u * 256;
        int r = unit >> 4, px4 = unit & 15;
        float4 v = *(const float4*)(in + (size_t)r * 1024 + px4 * 4);
        lds[r * 65 + px4 * 4 + 0] = v.x;
        lds[r * 65 + px4 * 4 + 1] = v.y;
        lds[r * 65 + px4 * 4 + 2] = v.z;
        lds[r * 65 + px4 * 4 + 3] = v.w;
    }
    __syncthreads();
#pragma unroll
    for (int u = 0; u < 2; ++u) {
        int unit = t + u * 256;
        int px = unit >> 3, cg = unit & 7;
        u16 pk[8];
#pragma unroll
        for (int j = 0; j < 8; ++j) pk[j] = f2bf(lds[(cg * 8 + j) * 65 + px]);
        *(int4*)&outp[px * 64 + cg * 8] = *(const int4*)pk;
    }
}

// ===========================================================================
// FF/W repack (after conv; w1p/w2p live in dead wpack region).
// ===========================================================================
__global__ __launch_bounds__(256) void repack_ff_kernel(
    const float* __restrict__ W1, const float* __restrict__ W2,
    u16* __restrict__ w1p, u16* __restrict__ w2p)
{
    int gid = blockIdx.x * 256 + threadIdx.x;   // 192*256 = 49152
    int f = gid >> 6, l = gid & 63;
    u16 pk[8];
    if (f < 512) {
        int ks = f >> 5, nf = f & 31;
#pragma unroll
        for (int j = 0; j < 8; ++j)
            pk[j] = f2bf(W1[(size_t)(ks * 32 + (l >> 4) * 8 + j) * 512 + nf * 16 + (l & 15)]);
        *(int4*)&w1p[(size_t)f * 512 + l * 8] = *(const int4*)pk;
    } else {
        int f2 = f - 512;
        int ks = f2 >> 4, nf = f2 & 15;
#pragma unroll
        for (int j = 0; j < 8; ++j)
            pk[j] = f2bf(W2[(size_t)(ks * 32 + (l >> 4) * 8 + j) * 256 + nf * 16 + (l & 15)]);
        *(int4*)&w2p[(size_t)f2 * 512 + l * 8] = *(const int4*)pk;
    }
}

// ===========================================================================
// MFMA implicit-GEMM conv (MFMA math validated R2; bf16 blocked staging).
// ===========================================================================
template<int K>
DEV void conv_mfma_body(const u16* __restrict__ srcb,
                        const u16* __restrict__ wsec,
                        float* __restrict__ dst,
                        u16* Bt, int y0, int cch0, int ncc, int t)
{
    constexpr int P = K / 2;
    const int w = t >> 6, l = t & 63;
    const int chi = l >> 4, ln = l & 15;
    const int rowbase = chi * 14 + w * 2 + 3 - P;
    const int colbase = ln + 3 - P;
    f32x4 acc[4][4];
#pragma unroll
    for (int m = 0; m < 4; ++m)
#pragma unroll
        for (int n = 0; n < 4; ++n) acc[m][n] = (f32x4){0.f, 0.f, 0.f, 0.f};

    for (int cc = 0; cc < ncc; ++cc) {
        const int ccg = cch0 + cc;
        __syncthreads();
        for (int u = 0; u < 9; ++u) {
            int unit = t + (u << 8);
            if (unit < 1792) {
                int xv = unit & 31, r = unit >> 5;
                int yy = r % 14, ch = r / 14;
                int ygl = y0 - 3 + yy;
                int4 pk;
                if ((unsigned)ygl < 32u)
                    pk = *(const int4*)&srcb[(size_t)ccg * 32768 + (ygl * 32 + xv) * 32 + ch * 8];
                else
                    pk = (int4){0, 0, 0, 0};
                *(int4*)&Bt[((ch * 14 + yy) * 40 + xv + 3) * 8] = pk;
            } else if (unit < 2240) {
                int hu = unit - 1792;
                int hx = hu & 7; int xi = hx < 3 ? hx : hx + 32;
                int r = hu >> 3; int yy = r % 14, ch = r / 14;
                int4 z = {0, 0, 0, 0};
                *(int4*)&Bt[((ch * 14 + yy) * 40 + xi) * 8] = z;
            }
        }
        __syncthreads();
        for (int dy = 0; dy < K; ++dy) {
#pragma unroll
            for (int dx = 0; dx < K; ++dx) {
                const int tap = dy * K + dx;
                const u16* wp = wsec + ((size_t)(tap * 8 + ccg) * 4) * 512 + l * 8;
                bf16x8 a0 = *(const bf16x8*)(wp);
                bf16x8 a1 = *(const bf16x8*)(wp + 512);
                bf16x8 a2 = *(const bf16x8*)(wp + 1024);
                bf16x8 a3 = *(const bf16x8*)(wp + 1536);
                bf16x8 bf[4];
#pragma unroll
                for (int n = 0; n < 4; ++n) {
                    int row = rowbase + dy + (n >> 1);
                    int col = colbase + dx + (n & 1) * 16;
                    bf[n] = *(const bf16x8*)&Bt[(row * 40 + col) * 8];
                }
#pragma unroll
                for (int n = 0; n < 4; ++n) {
                    acc[0][n] = __builtin_amdgcn_mfma_f32_16x16x32_bf16(a0, bf[n], acc[0][n], 0, 0, 0);
                    acc[1][n] = __builtin_amdgcn_mfma_f32_16x16x32_bf16(a1, bf[n], acc[1][n], 0, 0, 0);
                    acc[2][n] = __builtin_amdgcn_mfma_f32_16x16x32_bf16(a2, bf[n], acc[2][n], 0, 0, 0);
                    acc[3][n] = __builtin_amdgcn_mfma_f32_16x16x32_bf16(a3, bf[n], acc[3][n], 0, 0, 0);
                }
            }
        }
    }
#pragma unroll
    for (int m = 0; m < 4; ++m)
#pragma unroll
        for (int n = 0; n < 4; ++n) {
            int y = y0 + w * 2 + (n >> 1);
            int px = y * 32 + (n & 1) * 16 + ln;
            int ocb = m * 16 + chi * 4;
#pragma unroll
            for (int r = 0; r < 4; ++r)
                dst[(size_t)(ocb + r) * 1024 + px] = acc[m][n][r];
        }
}

__global__ __launch_bounds__(256) void conv_mfma_kernel(
    const u16* __restrict__ xbh, const u16* __restrict__ sbh,
    const u16* __restrict__ wpack,
    float* __restrict__ qb, float* __restrict__ kb, float* __restrict__ vb,
    float* __restrict__ p5, float* __restrict__ p7)
{
    __shared__ u16 Bt[4 * 14 * 40 * 8];
    const int bx = blockIdx.x, t = threadIdx.x;
    const int b = bx >> 7, r = bx & 127;
    if (r < 16) {
        int slot = r >> 2, yt = r & 3;
        conv_mfma_body<3>(xbh + (size_t)b * 262144,
                          wpack + (size_t)(slot * 288) * 512,
                          qb + ((size_t)b * 256 + slot * 64) * 1024,
                          Bt, yt * 8, 0, 8, t);
        return;
    }
    const int r2 = r - 16;
    const int side = r2 / 56, r3 = r2 % 56;
    const u16* sp = sbh + (size_t)b * 262144;
    float* fin = side ? vb : kb;
    const size_t wkb = 1152 + (size_t)side * 2688;
    if (r3 < 4) {
        conv_mfma_body<1>(sp, wpack + (wkb + 0) * 512,
                          fin + ((size_t)b * 256) * 1024, Bt, r3 * 8, 0, 8, t);
    } else if (r3 < 8) {
        conv_mfma_body<3>(sp, wpack + (wkb + 32) * 512,
                          fin + ((size_t)b * 256 + 64) * 1024, Bt, (r3 - 4) * 8, 0, 8, t);
    } else if (r3 < 24) {
        int t5 = r3 - 8, cpart = t5 >> 2, yt = t5 & 3;
        conv_mfma_body<5>(sp, wpack + (wkb + 320) * 512,
                          p5 + (((size_t)side * 4 + cpart) * 8 + b) * 65536,
                          Bt, yt * 8, cpart * 2, 2, t);
    } else {
        int t7 = r3 - 24, cpart = t7 >> 2, yt = t7 & 3;
        conv_mfma_body<7>(sp, wpack + (wkb + 1120) * 512,
                          p7 + (((size_t)side * 8 + cpart) * 8 + b) * 65536,
                          Bt, yt * 8, cpart, 1, t);
    }
}

__global__ __launch_bounds__(256) void reduce_kernel(
    const float* __restrict__ p5, const float* __restrict__ p7,
    float* __restrict__ kb, float* __restrict__ vb)
{
    int gid = blockIdx.x * 256 + threadIdx.x;   // 2048 blocks -> 524288 units
    int px4 = gid & 255;
    int rr = gid >> 8;
    int oc = rr & 63, b = (rr >> 6) & 7, head = (rr >> 9) & 1, side = rr >> 10;
    float* outb = side ? vb : kb;
    float4 s = make_float4(0.f, 0.f, 0.f, 0.f);
    if (head == 0) {
#pragma unroll
        for (int p = 0; p < 4; ++p) {
            float4 u = *((const float4*)(p5 + (((size_t)side * 4 + p) * 8 + b) * 65536 + (size_t)oc * 1024) + px4);
            s.x += u.x; s.y += u.y; s.z += u.z; s.w += u.w;
        }
        *((float4*)(outb + ((size_t)b * 256 + 128 + oc) * 1024) + px4) = s;
    } else {
#pragma unroll
        for (int p = 0; p < 8; ++p) {
            float4 u = *((const float4*)(p7 + (((size_t)side * 8 + p) * 8 + b) * 65536 + (size_t)oc * 1024) + px4);
            s.x += u.x; s.y += u.y; s.z += u.z; s.w += u.w;
        }
        *((float4*)(outb + ((size_t)b * 256 + 192 + oc) * 1024) + px4) = s;
    }
}

// ===========================================================================
// Fused QK^T + softmax -> vis (validated R4 math; bf16 staging).
// ===========================================================================
__global__ __launch_bounds__(512) void qk_sm_kernel(const u16* __restrict__ qbt,
                                                    const u16* __restrict__ kbt,
                                                    float* __restrict__ vis)
{
    __shared__ u16 kf[32 * 512];
    __shared__ u16 qf[4 * 512];
    __shared__ float redM[32 * 8];
    __shared__ float redS[32 * 8];
    const int t = threadIdx.x;
    const int bx = blockIdx.x;          // 8b*4h*32lt = 1024
    const int b = bx >> 7, h = (bx >> 5) & 3, l0 = (bx & 31) * 32;
    const u16* qtp = qbt + ((size_t)(b * 4 + h)) * 1024 * 64;
    const u16* ktp = kbt + ((size_t)(b * 4 + h)) * 1024 * 64;

    if (t < 256) {
        int r = t & 31, dblk = t >> 5;
        int4 pk = *(const int4*)&qtp[(size_t)(l0 + r) * 64 + dblk * 8];
        *(int4*)&qf[(((r >> 4) * 2 + (dblk >> 2)) * 64 + (dblk & 3) * 16 + (r & 15)) * 8] = pk;
    }
    __syncthreads();

    const int w = t >> 6, l = t & 63, ln = l & 15, lg = l >> 4;
    bf16x8 a[2][2];
#pragma unroll
    for (int fr = 0; fr < 2; ++fr)
#pragma unroll
        for (int ks = 0; ks < 2; ++ks)
            a[fr][ks] = *(const bf16x8*)&qf[((fr * 2 + ks) * 64 + l) * 8];

    f32x4 acc[2][4][2];
#pragma unroll
    for (int fr = 0; fr < 2; ++fr)
#pragma unroll
        for (int cc = 0; cc < 4; ++cc)
#pragma unroll
            for (int f = 0; f < 2; ++f) acc[fr][cc][f] = (f32x4){0.f, 0.f, 0.f, 0.f};

#pragma unroll
    for (int cc = 0; cc < 4; ++cc) {
        __syncthreads();
#pragma unroll
        for (int it = 0; it < 4; ++it) {
            int unit = it * 512 + t;
            int sl = unit & 255, dblk = unit >> 8;
            int4 pk = *(const int4*)&ktp[(size_t)(cc * 256 + sl) * 64 + dblk * 8];
            *(int4*)&kf[(((sl >> 4) * 2 + (dblk >> 2)) * 64 + (dblk & 3) * 16 + (sl & 15)) * 8] = pk;
        }
        __syncthreads();
#pragma unroll
        for (int f = 0; f < 2; ++f) {
            int fg = (w * 2 + f) * 2;
            bf16x8 b0 = *(const bf16x8*)&kf[((fg + 0) * 64 + l) * 8];
            bf16x8 b1 = *(const bf16x8*)&kf[((fg + 1) * 64 + l) * 8];
#pragma unroll
            for (int fr = 0; fr < 2; ++fr) {
                acc[fr][cc][f] = __builtin_amdgcn_mfma_f32_16x16x32_bf16(a[fr][0], b0, acc[fr][cc][f], 0, 0, 0);
                acc[fr][cc][f] = __builtin_amdgcn_mfma_f32_16x16x32_bf16(a[fr][1], b1, acc[fr][cc][f], 0, 0, 0);
            }
        }
    }

#pragma unroll
    for (int fr = 0; fr < 2; ++fr)
#pragma unroll
        for (int cc = 0; cc < 4; ++cc)
#pragma unroll
            for (int f = 0; f < 2; ++f)
#pragma unroll
                for (int e = 0; e < 4; ++e) acc[fr][cc][f][e] *= 0.125f;

    float rmax[2][4];
#pragma unroll
    for (int fr = 0; fr < 2; ++fr)
#pragma unroll
        for (int reg = 0; reg < 4; ++reg) {
            float m = -1e30f;
#pragma unroll
            for (int cc = 0; cc < 4; ++cc)
#pragma unroll
                for (int f = 0; f < 2; ++f) m = fmaxf(m, acc[fr][cc][f][reg]);
#pragma unroll
            for (int off = 1; off < 16; off <<= 1) m = fmaxf(m, __shfl_xor(m, off));
            if (ln == 0) redM[(fr * 16 + lg * 4 + reg) * 8 + w] = m;
            rmax[fr][reg] = m;
        }
    __syncthreads();
#pragma unroll
    for (int fr = 0; fr < 2; ++fr)
#pragma unroll
        for (int reg = 0; reg < 4; ++reg) {
            int r = fr * 16 + lg * 4 + reg;
            float m = redM[r * 8];
#pragma unroll
            for (int ww = 1; ww < 8; ++ww) m = fmaxf(m, redM[r * 8 + ww]);
            rmax[fr][reg] = m;
        }
#pragma unroll
    for (int fr = 0; fr < 2; ++fr)
#pragma unroll
        for (int reg = 0; reg < 4; ++reg) {
            float s = 0.f;
            float m = rmax[fr][reg];
#pragma unroll
            for (int cc = 0; cc < 4; ++cc)
#pragma unroll
                for (int f = 0; f < 2; ++f) {
                    float e = __expf(acc[fr][cc][f][reg] - m);
                    acc[fr][cc][f][reg] = e;
                    s += e;
                }
#pragma unroll
            for (int off = 1; off < 16; off <<= 1) s += __shfl_xor(s, off);
            if (ln == 0) redS[(fr * 16 + lg * 4 + reg) * 8 + w] = s;
        }
    __syncthreads();
    float* visp = vis + (((size_t)(b * 4 + h)) << 20);
#pragma unroll
    for (int fr = 0; fr < 2; ++fr)
#pragma unroll
        for (int reg = 0; reg < 4; ++reg) {
            int r = fr * 16 + lg * 4 + reg;
            float s = redS[r * 8] + redS[r * 8 + 1] + redS[r * 8 + 2] + redS[r * 8 + 3]
                    + redS[r * 8 + 4] + redS[r * 8 + 5] + redS[r * 8 + 6] + redS[r * 8 + 7];
            float inv = 1.f / s;
            float* vr = visp + (size_t)(l0 + r) * 1024 + w * 32 + ln;
#pragma unroll
            for (int cc = 0; cc < 4; ++cc)
#pragma unroll
                for (int f = 0; f < 2; ++f)
                    vr[cc * 256 + f * 16] = acc[fr][cc][f][reg] * inv;
        }
}

// ---------------------------------------------------------------------------
// Linear attention (validated R2).
// ---------------------------------------------------------------------------
__global__ __launch_bounds__(256) void kv_kernel(const float* __restrict__ k,
                                                 const float* __restrict__ v,
                                                 float* __restrict__ KVp,
                                                 float* __restrict__ Ksump)
{
    __shared__ float4 Kt4[64*17];
    __shared__ float4 Vt4[64*16];
    float* Kt = (float*)Kt4;
    float* Vt = (float*)Vt4;
    const int t = threadIdx.x;
    const int bx = blockIdx.x;
    const int b = bx >> 4, h = (bx >> 2) & 3, ch = bx & 3;
    const float* kb = k + ((size_t)b*256 + h*64)*1024 + ch*256;
    const float* vb = v + ((size_t)b*256 + h*64)*1024 + ch*256;
    const int d = t >> 2, v0 = (t & 3) * 16;
    float4 acc[4];
#pragma unroll
    for (int j = 0; j < 4; ++j) acc[j] = make_float4(0.f, 0.f, 0.f, 0.f);
    float ks = 0.f;
    for (int st = 0; st < 4; ++st) {
        __syncthreads();
        {
            int dd = t >> 2, r0 = (t & 3) * 16;
#pragma unroll
            for (int mm = 0; mm < 4; ++mm) {
                float4 kv = *(const float4*)(kb + dd*1024 + st*64 + r0 + mm*4);
                Kt[(r0+mm*4+0)*68 + dd] = elu1(kv.x);
                Kt[(r0+mm*4+1)*68 + dd] = elu1(kv.y);
                Kt[(r0+mm*4+2)*68 + dd] = elu1(kv.z);
                Kt[(r0+mm*4+3)*68 + dd] = elu1(kv.w);
                float4 vv = *(const float4*)(vb + dd*1024 + st*64 + r0 + mm*4);
                Vt[(r0+mm*4+0)*64 + dd] = vv.x;
                Vt[(r0+mm*4+1)*64 + dd] = vv.y;
                Vt[(r0+mm*4+2)*64 + dd] = vv.z;
                Vt[(r0+mm*4+3)*64 + dd] = vv.w;
            }
        }
        __syncthreads();
#pragma unroll 8
        for (int s = 0; s < 64; ++s) {
            float kf = Kt[s*68 + d];
            const float4* vp = (const float4*)(Vt + s*64 + v0);
#pragma unroll
            for (int j = 0; j < 4; ++j) {
                float4 vv = vp[j];
                acc[j].x += kf*vv.x; acc[j].y += kf*vv.y;
                acc[j].z += kf*vv.z; acc[j].w += kf*vv.w;
            }
        }
        if (t < 64) {
#pragma unroll 8
            for (int s = 0; s < 64; ++s) ks += Kt[s*68 + t];
        }
    }
    float* op = KVp + ((size_t)((ch*32 + b*4 + h)*64 + d))*64 + v0;
#pragma unroll
    for (int j = 0; j < 4; ++j) ((float4*)op)[j] = acc[j];
    if (t < 64) Ksump[(size_t)(ch*32 + b*4 + h)*64 + t] = ks;
}

__global__ __launch_bounds__(256) void msg_kernel(const float* __restrict__ q,
                                                  const float* __restrict__ KVp,
                                                  const float* __restrict__ Ksump,
                                                  float* __restrict__ msg)
{
    __shared__ float4 kvl4[4*1028];
    __shared__ float ksl[4*65];
    float* kvl = (float*)kvl4;
    const int t = threadIdx.x;
    const int bx = blockIdx.x;
    const int b = bx >> 4;
    const int l0 = (bx & 15) * 64;
    for (int m = 0; m < 64; ++m) {
        int idx = t + 256*m;
        int hh = idx >> 12, dd = (idx >> 6) & 63, vv = idx & 63;
        float s = 0.f;
#pragma unroll
        for (int ch = 0; ch < 4; ++ch)
            s += KVp[(size_t)((ch*32 + b*4))*4096 + idx];
        kvl[hh*4112 + dd*64 + vv] = s;
    }
    {
        float s = 0.f;
#pragma unroll
        for (int ch = 0; ch < 4; ++ch)
            s += Ksump[(size_t)(ch*32 + b*4)*64 + t];
        ksl[(t >> 6)*65 + (t & 63)] = s;
    }
    __syncthreads();
    const int h = t & 3, l = l0 + (t >> 2);
    const float* qb = q + ((size_t)b*256 + h*64)*1024 + l;
    float qf[64];
#pragma unroll
    for (int dd = 0; dd < 64; ++dd) qf[dd] = elu1(qb[dd*1024]);
    float zd = 1e-6f;
#pragma unroll
    for (int dd = 0; dd < 64; ++dd) zd += qf[dd] * ksl[h*65 + dd];
    const float Z = 1.f / zd;
    float* op = msg + ((size_t)(b*1024 + l))*256 + h*64;
    for (int c0 = 0; c0 < 64; c0 += 16) {
        float4 a[4];
#pragma unroll
        for (int j = 0; j < 4; ++j) a[j] = make_float4(0.f, 0.f, 0.f, 0.f);
#pragma unroll
        for (int dd = 0; dd < 64; ++dd) {
            float qv = qf[dd];
            const float4* kp = (const float4*)(kvl + h*4112 + dd*64 + c0);
#pragma unroll
            for (int j = 0; j < 4; ++j) {
                float4 kk = kp[j];
                a[j].x += qv*kk.x; a[j].y += qv*kk.y;
                a[j].z += qv*kk.z; a[j].w += qv*kk.w;
            }
        }
#pragma unroll
        for (int j = 0; j < 4; ++j) {
            a[j].x *= Z; a[j].y *= Z; a[j].z *= Z; a[j].w *= Z;
            ((float4*)(op + c0))[j] = a[j];
        }
    }
}

__global__ __launch_bounds__(256) void merge_ln1_kernel(const float* __restrict__ msg,
                                                        const float* __restrict__ Wm,
                                                        const float* __restrict__ g1,
                                                        const float* __restrict__ b1,
                                                        float* __restrict__ msgm)
{
    __shared__ float4 mL4[16*65];
    __shared__ float mv[32];
    float* mL = (float*)mL4;
    const int t = threadIdx.x;
    const size_t base = (size_t)blockIdx.x * 16;
    {
        int r = t >> 4, cb = t & 15;
#pragma unroll
        for (int j = 0; j < 16; ++j)
            mL[r*260 + cb + 16*j] = msg[(base + r)*256 + cb + 16*j];
    }
    __syncthreads();
    float acc[16];
#pragma unroll
    for (int r = 0; r < 16; ++r) acc[r] = 0.f;
    for (int i = 0; i < 256; i += 4) {
        float w0 = Wm[(size_t)(i+0)*256 + t];
        float w1 = Wm[(size_t)(i+1)*256 + t];
        float w2 = Wm[(size_t)(i+2)*256 + t];
        float w3 = Wm[(size_t)(i+3)*256 + t];
#pragma unroll
        for (int r = 0; r < 16; ++r) {
            float4 m4 = mL4[r*65 + (i >> 2)];
            acc[r] += m4.x*w0 + m4.y*w1 + m4.z*w2 + m4.w*w3;
        }
    }
    __syncthreads();
#pragma unroll
    for (int r = 0; r < 16; ++r) mL[r*260 + t] = acc[r];
    __syncthreads();
    {
        int wid = t >> 6, lane = t & 63;
#pragma unroll
        for (int rr = 0; rr < 4; ++rr) {
            int r = wid*4 + rr;
            float s1 = 0.f, s2 = 0.f;
#pragma unroll
            for (int m = 0; m < 4; ++m) {
                float vv = mL[r*260 + lane + 64*m];
                s1 += vv; s2 += vv*vv;
            }
#pragma unroll
            for (int off = 1; off < 64; off <<= 1) {
                s1 += __shfl_xor(s1, off);
                s2 += __shfl_xor(s2, off);
            }
            if (lane == 0) {
                float mean = s1 * (1.f/256.f);
                float var  = s2 * (1.f/256.f) - mean*mean;
                mv[r*2]   = mean;
                mv[r*2+1] = rsqrtf(var + 1e-5f);
            }
        }
    }
    __syncthreads();
    const float gg = g1[t], bb = b1[t];
#pragma unroll
    for (int r = 0; r < 16; ++r) {
        float val = (mL[r*260 + t] - mv[r*2]) * mv[r*2+1] * gg + bb;
        msgm[(base + r)*256 + t] = val;
    }
}

// ===========================================================================
// FF via MFMA (validated R4).
// ===========================================================================
__global__ __launch_bounds__(256) void ff_mfma_kernel(
    const float* __restrict__ x, const float* __restrict__ msgm,
    const u16* __restrict__ w1p, const u16* __restrict__ w2p,
    const float* __restrict__ g2, const float* __restrict__ b2,
    float* __restrict__ out)
{
    __shared__ u16 tile[32 * 520];
    __shared__ float redS[32 * 4];
    __shared__ float redQ[32 * 4];
    float* tf = (float*)tile;
    const int t = threadIdx.x;
    const int base = blockIdx.x * 32;       // 256 blocks
    const int b = base >> 10, l0 = base & 1023;
    const int w = t >> 6, l = t & 63, ln = l & 15, lg = l >> 4;

    {
        int rr = t & 31, cg = t >> 5;
        for (int cci = 0; cci < 32; ++cci) {
            int c = cci * 8 + cg;
            float v = x[((size_t)b * 256 + c) * 1024 + l0 + rr];
            tile[rr * 520 + c] = f2bf(v);
        }
        int r = t >> 3, cb = (t & 7) * 32;
#pragma unroll
        for (int i = 0; i < 8; ++i) {
            float4 v = *(const float4*)&msgm[((size_t)(base + r)) * 256 + cb + i * 4];
            u32 p0 = (u32)f2bf(v.x) | ((u32)f2bf(v.y) << 16);
            u32 p1 = (u32)f2bf(v.z) | ((u32)f2bf(v.w) << 16);
            *(u32*)&tile[r * 520 + 256 + cb + i * 4] = p0;
            *(u32*)&tile[r * 520 + 256 + cb + i * 4 + 2] = p1;
        }
    }
    __syncthreads();

    f32x4 acc[2][8];
#pragma unroll
    for (int fr = 0; fr < 2; ++fr)
#pragma unroll
        for (int fc = 0; fc < 8; ++fc) acc[fr][fc] = (f32x4){0.f, 0.f, 0.f, 0.f};
    for (int ks = 0; ks < 16; ++ks) {
        bf16x8 a0 = *(const bf16x8*)&tile[(ln) * 520 + ks * 32 + lg * 8];
        bf16x8 a1 = *(const bf16x8*)&tile[(16 + ln) * 520 + ks * 32 + lg * 8];
#pragma unroll
        for (int fc = 0; fc < 8; ++fc) {
            bf16x8 bb = *(const bf16x8*)&w1p[((size_t)(ks * 32 + w * 8 + fc) * 64 + l) * 8];
            acc[0][fc] = __builtin_amdgcn_mfma_f32_16x16x32_bf16(a0, bb, acc[0][fc], 0, 0, 0);
            acc[1][fc] = __builtin_amdgcn_mfma_f32_16x16x32_bf16(a1, bb, acc[1][fc], 0, 0, 0);
        }
    }
    __syncthreads();
#pragma unroll
    for (int fr = 0; fr < 2; ++fr)
#pragma unroll
        for (int fc = 0; fc < 8; ++fc)
#pragma unroll
            for (int reg = 0; reg < 4; ++reg) {
                int r = fr * 16 + lg * 4 + reg;
                int c = w * 128 + fc * 16 + ln;
                tile[r * 520 + c] = f2bf(fmaxf(acc[fr][fc][reg], 0.f));
            }
    __syncthreads();

    f32x4 acc2[2][4];
#pragma unroll
    for (int fr = 0; fr < 2; ++fr)
#pragma unroll
        for (int fc = 0; fc < 4; ++fc) acc2[fr][fc] = (f32x4){0.f, 0.f, 0.f, 0.f};
    for (int ks = 0; ks < 16; ++ks) {
        bf16x8 a0 = *(const bf16x8*)&tile[(ln) * 520 + ks * 32 + lg * 8];
        bf16x8 a1 = *(const bf16x8*)&tile[(16 + ln) * 520 + ks * 32 + lg * 8];
#pragma unroll
        for (int fc = 0; fc < 4; ++fc) {
            bf16x8 bb = *(const bf16x8*)&w2p[((size_t)(ks * 16 + w * 4 + fc) * 64 + l) * 8];
            acc2[0][fc] = __builtin_amdgcn_mfma_f32_16x16x32_bf16(a0, bb, acc2[0][fc], 0, 0, 0);
            acc2[1][fc] = __builtin_amdgcn_mfma_f32_16x16x32_bf16(a1, bb, acc2[1][fc], 0, 0, 0);
        }
    }
#pragma unroll
    for (int fr = 0; fr < 2; ++fr)
#pragma unroll
        for (int reg = 0; reg < 4; ++reg) {
            float s = 0.f, qsum = 0.f;
#pragma unroll
            for (int fc = 0; fc < 4; ++fc) {
                float v = acc2[fr][fc][reg];
                s += v; qsum += v * v;
            }
#pragma unroll
            for (int off = 1; off < 16; off <<= 1) {
                s += __shfl_xor(s, off);
                qsum += __shfl_xor(qsum, off);
            }
            if (ln == 0) {
                int r = fr * 16 + lg * 4 + reg;
                redS[r * 4 + w] = s;
                redQ[r * 4 + w] = qsum;
            }
        }
    __syncthreads();
    float mean[2][4], rstd[2][4];
#pragma unroll
    for (int fr = 0; fr < 2; ++fr)
#pragma unroll
        for (int reg = 0; reg < 4; ++reg) {
            int r = fr * 16 + lg * 4 + reg;
            float s = redS[r * 4] + redS[r * 4 + 1] + redS[r * 4 + 2] + redS[r * 4 + 3];
            float qs = redQ[r * 4] + redQ[r * 4 + 1] + redQ[r * 4 + 2] + redQ[r * 4 + 3];
            float m = s * (1.f / 256.f);
            mean[fr][reg] = m;
            rstd[fr][reg] = rsqrtf(qs * (1.f / 256.f) - m * m + 1e-5f);
        }
#pragma unroll
    for (int fc = 0; fc < 4; ++fc) {
        int c = w * 64 + fc * 16 + ln;
        float gg = g2[c], bb = b2[c];
#pragma unroll
        for (int fr = 0; fr < 2; ++fr)
#pragma unroll
            for (int reg = 0; reg < 4; ++reg) {
                int r = fr * 16 + lg * 4 + reg;
                tf[r * 260 + c] = (acc2[fr][fc][reg] - mean[fr][reg]) * rstd[fr][reg] * gg + bb;
            }
    }
    __syncthreads();
    {
        const float* xp = x + ((size_t)b * 256 + t) * 1024 + l0;
        float* op = out + ((size_t)b * 256 + t) * 1024 + l0;
#pragma unroll
        for (int i = 0; i < 8; ++i) {
            float4 xv = *(const float4*)(xp + i * 4);
            float4 o;
            o.x = xv.x + tf[(i * 4 + 0) * 260 + t];
            o.y = xv.y + tf[(i * 4 + 1) * 260 + t];
            o.z = xv.z + tf[(i * 4 + 2) * 260 + t];
            o.w = xv.w + tf[(i * 4 + 3) * 260 + t];
            *(float4*)(op + i * 4) = o;
        }
    }
}

// ---------------------------------------------------------------------------
extern "C" void kernel_launch(void* const* d_in, const int* in_sizes, int n_in,
                              void* d_out, int out_size, void* d_ws, size_t ws_size,
                              hipStream_t stream)
{
    const float* x    = (const float*)d_in[0];
    const float* src  = (const float*)d_in[1];
    const float* Wq   = (const float*)d_in[2];
    const float* Wk1  = (const float*)d_in[3];
    const float* Wk3  = (const float*)d_in[4];
    const float* Wk5  = (const float*)d_in[5];
    const float* Wk7  = (const float*)d_in[6];
    const float* Wv1  = (const float*)d_in[7];
    const float* Wv3  = (const float*)d_in[8];
    const float* Wv5  = (const float*)d_in[9];
    const float* Wv7  = (const float*)d_in[10];
    const float* Wm   = (const float*)d_in[11];
    const float* g1   = (const float*)d_in[12];
    const float* b1   = (const float*)d_in[13];
    const float* g2   = (const float*)d_in[14];
    const float* b2   = (const float*)d_in[15];
    const float* W1   = (const float*)d_in[16];
    const float* W2   = (const float*)d_in[17];

    float* out = (float*)d_out;
    float* vis = out + 2097152;          // [b,h,l,s] (33.55M floats)

    // Conv partials in vis region (dead until qk_sm overwrites all of it).
    float* p5 = vis;                     // [2][4][8][64][1024] = 4.19M floats
    float* p7 = vis + 4194304;           // [2][8][8][64][1024] = 8.39M floats

    // ws extent+lifetime map (float offsets; bf16 arrays show float-equivalent):
    //  qb    [0,        2097152)  conv..msg_kernel
    //  kb    [2097152,  4194304)  conv..kv/cast_qk
    //  vb    [4194304,  6291456)  conv..kv
    //  wpack [6291456,  7962624)  repack..conv
    //    then w1p [6291456, 6422528) repack_ff..ff
    //         w2p [6422528, 6488064) repack_ff..ff
    //         qbt [6488064, 7536640) cast_qk..qk_sm   (1,048,576 floats)
    //         kbt [7536640, 8585216) cast_qk..qk_sm   (overlaps dead xbh)
    //  xbh   [7962624,  9011200)  cast_src..conv      (1,048,576 floats)
    //  sbh   [9011200, 10059776)  cast_src..conv      (1,048,576 floats)
    //    then msg [7962624, 10059776) msg_kernel..merge (after qk_sm: kbt dead)
    //  msgm  [10059776, 12156928)  merge..ff
    //  KVp   [12156928, 12681216), Ksump [12681216, 12689408)
    float* ws    = (float*)d_ws;
    float* qb    = ws;
    float* kb    = ws + 2097152;
    float* vb    = ws + 4194304;
    u16*   wpack = (u16*)(ws + 6291456);
    u16*   w1p   = (u16*)(ws + 6291456);
    u16*   w2p   = (u16*)(ws + 6422528);
    u16*   qbt   = (u16*)(ws + 6488064);
    u16*   kbt   = (u16*)(ws + 7536640);
    u16*   xbh   = (u16*)(ws + 7962624);
    u16*   sbh   = (u16*)(ws + 9011200);
    float* msg   = ws + 7962624;
    float* msgm  = ws + 10059776;
    float* KVp   = ws + 12156928;
    float* Ksump = ws + 12681216;

    repack_kernel   <<<1632, 256, 0, stream>>>(Wq, Wk1, Wk3, Wk5, Wk7,
                                               Wv1, Wv3, Wv5, Wv7, wpack);
    cast_src_kernel <<<1024, 256, 0, stream>>>(x, src, xbh, sbh);
    conv_mfma_kernel<<<1024, 256, 0, stream>>>(xbh, sbh, wpack, qb, kb, vb, p5, p7);
    reduce_kernel   <<<2048, 256, 0, stream>>>(p5, p7, kb, vb);
    repack_ff_kernel<<<192,  256, 0, stream>>>(W1, W2, w1p, w2p);
    cast_qk_kernel  <<<1024, 256, 0, stream>>>(qb, kb, qbt, kbt);
    qk_sm_kernel    <<<1024, 512, 0, stream>>>(qbt, kbt, vis);
    kv_kernel       <<<128,  256, 0, stream>>>(kb, vb, KVp, Ksump);
    msg_kernel      <<<128,  256, 0, stream>>>(qb, KVp, Ksump, msg);
    merge_ln1_kernel<<<512,  256, 0, stream>>>(msg, Wm, g1, b1, msgm);
    ff_mfma_kernel  <<<256,  256, 0, stream>>>(x, msgm, w1p, w2p, g2, b2, out);
}

// Round 7
// 308.798 us; speedup vs baseline: 11.4230x; 1.0090x over previous
//
#include <hip/hip_runtime.h>

#define DEV __device__ __forceinline__

typedef unsigned short u16;
typedef unsigned int u32;
typedef __bf16 bf16x8 __attribute__((ext_vector_type(8)));
typedef float f32x4 __attribute__((ext_vector_type(4)));

DEV float elu1(float x) { return x > 0.f ? x + 1.f : __expf(x); }

DEV u16 f2bf(float f) {
    union { float f; unsigned u; } v; v.f = f;
    unsigned r = v.u + 0x7fffu + ((v.u >> 16) & 1u);
    return (u16)(r >> 16);
}

// ===========================================================================
// Conv weight repack (validated R2).
// ===========================================================================
__global__ __launch_bounds__(256) void repack_kernel(
    const float* __restrict__ Wq,
    const float* __restrict__ Wk1, const float* __restrict__ Wk3,
    const float* __restrict__ Wk5, const float* __restrict__ Wk7,
    const float* __restrict__ Wv1, const float* __restrict__ Wv3,
    const float* __restrict__ Wv5, const float* __restrict__ Wv7,
    u16* __restrict__ wpack)
{
    int gid = blockIdx.x * 256 + threadIdx.x;
    int frag = gid >> 6, l = gid & 63;
    const float* W; int K, ocbase = 0, rel;
    if (frag < 1152) {
        W = Wq; K = 3; int slot = frag / 288; rel = frag % 288; ocbase = slot * 64;
    } else {
        int f = frag - 1152; int side = f / 2688; f %= 2688;
        if (f < 32)        { W = side ? Wv1 : Wk1; K = 1; rel = f; }
        else if (f < 320)  { W = side ? Wv3 : Wk3; K = 3; rel = f - 32; }
        else if (f < 1120) { W = side ? Wv5 : Wk5; K = 5; rel = f - 320; }
        else               { W = side ? Wv7 : Wk7; K = 7; rel = f - 1120; }
    }
    int og = rel & 3, cc = (rel >> 2) & 7, tap = rel >> 5;
    int dy = tap / K, dx = tap % K;
    int oc = ocbase + og * 16 + (l & 15);
    int c0 = cc * 32 + (l >> 4) * 8;
    u16 pk[8];
#pragma unroll
    for (int j = 0; j < 8; ++j)
        pk[j] = f2bf(W[((size_t)(oc * 256 + c0 + j) * K + dy) * K + dx]);
    *(int4*)&wpack[(size_t)frag * 512 + l * 8] = *(const int4*)pk;
}

// ===========================================================================
// cast_src: fp32 NCHW -> bf16 blocked [b][cc8][pix1024][c32].
// ===========================================================================
__global__ __launch_bounds__(256) void cast_src_kernel(
    const float* __restrict__ x, const float* __restrict__ src,
    u16* __restrict__ xbh, u16* __restrict__ sbh)
{
    __shared__ float lds[32 * 129];
    const int i = blockIdx.x, t = threadIdx.x;   // 1024 blocks
    const int inp = i >> 9, rem = i & 511;
    const int b = rem >> 6, cc = (rem >> 3) & 7, pxb = rem & 7;
    const float* in = (inp ? src : x) + ((size_t)b * 256 + cc * 32) * 1024 + pxb * 128;
    u16* outp = (inp ? sbh : xbh) + (size_t)b * 262144 + (size_t)cc * 32768 + pxb * 128 * 32;
#pragma unroll
    for (int u = 0; u < 4; ++u) {
        int unit = t + u * 256;
        int r = unit >> 5, px4 = unit & 31;
        float4 v = *(const float4*)(in + (size_t)r * 1024 + px4 * 4);
        lds[r * 129 + px4 * 4 + 0] = v.x;
        lds[r * 129 + px4 * 4 + 1] = v.y;
        lds[r * 129 + px4 * 4 + 2] = v.z;
        lds[r * 129 + px4 * 4 + 3] = v.w;
    }
    __syncthreads();
#pragma unroll
    for (int u = 0; u < 2; ++u) {
        int unit = t + u * 256;
        int px = unit >> 2, cg = unit & 3;
        u16 pk[8];
#pragma unroll
        for (int j = 0; j < 8; ++j) pk[j] = f2bf(lds[(cg * 8 + j) * 129 + px]);
        *(int4*)&outp[px * 32 + cg * 8] = *(const int4*)pk;
    }
}

// ===========================================================================
// cast_qk: qb/kb fp32 [b][c][l] -> bf16 [b*4+h][l][64].
// ===========================================================================
__global__ __launch_bounds__(256) void cast_qk_kernel(
    const float* __restrict__ qb, const float* __restrict__ kb,
    u16* __restrict__ qbt, u16* __restrict__ kbt)
{
    __shared__ float lds[64 * 65];
    const int i = blockIdx.x, t = threadIdx.x;   // 1024 blocks
    const int inp = i >> 9, rem = i & 511;
    const int b = rem >> 6, h = (rem >> 4) & 3, pxb = rem & 15;
    const float* in = (inp ? kb : qb) + ((size_t)b * 256 + h * 64) * 1024 + pxb * 64;
    u16* outp = (inp ? kbt : qbt) + (((size_t)(b * 4 + h)) * 1024 + pxb * 64) * 64;
#pragma unroll
    for (int u = 0; u < 4; ++u) {
        int unit = t + u * 256;
        int r = unit >> 4, px4 = unit & 15;
        float4 v = *(const float4*)(in + (size_t)r * 1024 + px4 * 4);
        lds[r * 65 + px4 * 4 + 0] = v.x;
        lds[r * 65 + px4 * 4 + 1] = v.y;
        lds[r * 65 + px4 * 4 + 2] = v.z;
        lds[r * 65 + px4 * 4 + 3] = v.w;
    }
    __syncthreads();
#pragma unroll
    for (int u = 0; u < 2; ++u) {
        int unit = t + u * 256;
        int px = unit >> 3, cg = unit & 7;
        u16 pk[8];
#pragma unroll
        for (int j = 0; j < 8; ++j) pk[j] = f2bf(lds[(cg * 8 + j) * 65 + px]);
        *(int4*)&outp[px * 64 + cg * 8] = *(const int4*)pk;
    }
}

// ===========================================================================
// FF/W repack (after conv; w1p/w2p live in dead wpack region).
// ===========================================================================
__global__ __launch_bounds__(256) void repack_ff_kernel(
    const float* __restrict__ W1, const float* __restrict__ W2,
    u16* __restrict__ w1p, u16* __restrict__ w2p)
{
    int gid = blockIdx.x * 256 + threadIdx.x;   // 192*256 = 49152
    int f = gid >> 6, l = gid & 63;
    u16 pk[8];
    if (f < 512) {
        int ks = f >> 5, nf = f & 31;
#pragma unroll
        for (int j = 0; j < 8; ++j)
            pk[j] = f2bf(W1[(size_t)(ks * 32 + (l >> 4) * 8 + j) * 512 + nf * 16 + (l & 15)]);
        *(int4*)&w1p[(size_t)f * 512 + l * 8] = *(const int4*)pk;
    } else {
        int f2 = f - 512;
        int ks = f2 >> 4, nf = f2 & 15;
#pragma unroll
        for (int j = 0; j < 8; ++j)
            pk[j] = f2bf(W2[(size_t)(ks * 32 + (l >> 4) * 8 + j) * 256 + nf * 16 + (l & 15)]);
        *(int4*)&w2p[(size_t)f2 * 512 + l * 8] = *(const int4*)pk;
    }
}

// ===========================================================================
// MFMA implicit-GEMM conv: 512 threads (8 waves), 64 oc x 512 px (16 rows).
// LDS B-tile [ch4][yy22][x40][c8] bf16, zero halo (pad 3 both sides, rows
// y0-3..y0+18). Wave w: rows w*2, w*2+1. MFMA/tap math validated R2.
// ===========================================================================
template<int K>
DEV void conv_mfma_body(const u16* __restrict__ srcb,
                        const u16* __restrict__ wsec,
                        float* __restrict__ dst,
                        u16* Bt, int y0, int cch0, int ncc, int t)
{
    constexpr int P = K / 2;
    const int w = t >> 6, l = t & 63;
    const int chi = l >> 4, ln = l & 15;
    const int rowbase = chi * 22 + w * 2 + 3 - P;
    const int colbase = ln + 3 - P;
    f32x4 acc[4][4];
#pragma unroll
    for (int m = 0; m < 4; ++m)
#pragma unroll
        for (int n = 0; n < 4; ++n) acc[m][n] = (f32x4){0.f, 0.f, 0.f, 0.f};

    for (int cc = 0; cc < ncc; ++cc) {
        const int ccg = cch0 + cc;
        __syncthreads();
        // stage 22 rows (halo pad 3): main 2816 units, halo 704; 7 iters x 512
#pragma unroll
        for (int u = 0; u < 7; ++u) {
            int unit = t + (u << 9);
            if (unit < 2816) {
                int xv = unit & 31, r = unit >> 5;   // r<88
                int yy = r % 22, ch = r / 22;
                int ygl = y0 - 3 + yy;
                int4 pk;
                if ((unsigned)ygl < 32u)
                    pk = *(const int4*)&srcb[(size_t)ccg * 32768 + (ygl * 32 + xv) * 32 + ch * 8];
                else
                    pk = (int4){0, 0, 0, 0};
                *(int4*)&Bt[((ch * 22 + yy) * 40 + xv + 3) * 8] = pk;
            } else if (unit < 3520) {
                int hu = unit - 2816;
                int hx = hu & 7; int xi = hx < 3 ? hx : hx + 32;
                int r = hu >> 3; int yy = r % 22, ch = r / 22;
                int4 z = {0, 0, 0, 0};
                *(int4*)&Bt[((ch * 22 + yy) * 40 + xi) * 8] = z;
            }
        }
        __syncthreads();
#pragma unroll
        for (int dy = 0; dy < K; ++dy) {
#pragma unroll
            for (int dx = 0; dx < K; ++dx) {
                const int tap = dy * K + dx;
                const u16* wp = wsec + ((size_t)(tap * 8 + ccg) * 4) * 512 + l * 8;
                bf16x8 a0 = *(const bf16x8*)(wp);
                bf16x8 a1 = *(const bf16x8*)(wp + 512);
                bf16x8 a2 = *(const bf16x8*)(wp + 1024);
                bf16x8 a3 = *(const bf16x8*)(wp + 1536);
                bf16x8 bf[4];
#pragma unroll
                for (int n = 0; n < 4; ++n) {
                    int row = rowbase + dy + (n >> 1);
                    int col = colbase + dx + (n & 1) * 16;
                    bf[n] = *(const bf16x8*)&Bt[(row * 40 + col) * 8];
                }
#pragma unroll
                for (int n = 0; n < 4; ++n) {
                    acc[0][n] = __builtin_amdgcn_mfma_f32_16x16x32_bf16(a0, bf[n], acc[0][n], 0, 0, 0);
                    acc[1][n] = __builtin_amdgcn_mfma_f32_16x16x32_bf16(a1, bf[n], acc[1][n], 0, 0, 0);
                    acc[2][n] = __builtin_amdgcn_mfma_f32_16x16x32_bf16(a2, bf[n], acc[2][n], 0, 0, 0);
                    acc[3][n] = __builtin_amdgcn_mfma_f32_16x16x32_bf16(a3, bf[n], acc[3][n], 0, 0, 0);
                }
            }
        }
    }
#pragma unroll
    for (int m = 0; m < 4; ++m)
#pragma unroll
        for (int n = 0; n < 4; ++n) {
            int y = y0 + w * 2 + (n >> 1);
            int px = y * 32 + (n & 1) * 16 + ln;
            int ocb = m * 16 + chi * 4;
#pragma unroll
            for (int r = 0; r < 4; ++r)
                dst[(size_t)(ocb + r) * 1024 + px] = acc[m][n][r];
        }
}

// Job decode: 64 blocks/batch, grid 512.
//  r<8: q slot r>>1, yt r&1 (full c)
//  else r2=r-8, side=r2/28, r3=r2%28:
//   r3<2: K1 yt=r3; r3<4: K3 yt=r3-2; r3<12: K5 (4 cparts x 2cc, yt);
//   r3<28: K7 (8 cparts x 1cc, yt)
__global__ __launch_bounds__(512) void conv_mfma_kernel(
    const u16* __restrict__ xbh, const u16* __restrict__ sbh,
    const u16* __restrict__ wpack,
    float* __restrict__ qb, float* __restrict__ kb, float* __restrict__ vb,
    float* __restrict__ p5, float* __restrict__ p7)
{
    __shared__ u16 Bt[4 * 22 * 40 * 8];
    const int bx = blockIdx.x, t = threadIdx.x;
    const int b = bx >> 6, r = bx & 63;
    if (r < 8) {
        int slot = r >> 1, yt = r & 1;
        conv_mfma_body<3>(xbh + (size_t)b * 262144,
                          wpack + (size_t)(slot * 288) * 512,
                          qb + ((size_t)b * 256 + slot * 64) * 1024,
                          Bt, yt * 16, 0, 8, t);
        return;
    }
    const int r2 = r - 8;
    const int side = r2 / 28, r3 = r2 % 28;
    const u16* sp = sbh + (size_t)b * 262144;
    float* fin = side ? vb : kb;
    const size_t wkb = 1152 + (size_t)side * 2688;
    if (r3 < 2) {
        conv_mfma_body<1>(sp, wpack + (wkb + 0) * 512,
                          fin + ((size_t)b * 256) * 1024, Bt, r3 * 16, 0, 8, t);
    } else if (r3 < 4) {
        conv_mfma_body<3>(sp, wpack + (wkb + 32) * 512,
                          fin + ((size_t)b * 256 + 64) * 1024, Bt, (r3 - 2) * 16, 0, 8, t);
    } else if (r3 < 12) {
        int t5 = r3 - 4, cpart = t5 >> 1, yt = t5 & 1;
        conv_mfma_body<5>(sp, wpack + (wkb + 320) * 512,
                          p5 + (((size_t)side * 4 + cpart) * 8 + b) * 65536,
                          Bt, yt * 16, cpart * 2, 2, t);
    } else {
        int t7 = r3 - 12, cpart = t7 >> 1, yt = t7 & 1;
        conv_mfma_body<7>(sp, wpack + (wkb + 1120) * 512,
                          p7 + (((size_t)side * 8 + cpart) * 8 + b) * 65536,
                          Bt, yt * 16, cpart, 1, t);
    }
}

__global__ __launch_bounds__(256) void reduce_kernel(
    const float* __restrict__ p5, const float* __restrict__ p7,
    float* __restrict__ kb, float* __restrict__ vb)
{
    int gid = blockIdx.x * 256 + threadIdx.x;   // 2048 blocks -> 524288 units
    int px4 = gid & 255;
    int rr = gid >> 8;
    int oc = rr & 63, b = (rr >> 6) & 7, head = (rr >> 9) & 1, side = rr >> 10;
    float* outb = side ? vb : kb;
    float4 s = make_float4(0.f, 0.f, 0.f, 0.f);
    if (head == 0) {
#pragma unroll
        for (int p = 0; p < 4; ++p) {
            float4 u = *((const float4*)(p5 + (((size_t)side * 4 + p) * 8 + b) * 65536 + (size_t)oc * 1024) + px4);
            s.x += u.x; s.y += u.y; s.z += u.z; s.w += u.w;
        }
        *((float4*)(outb + ((size_t)b * 256 + 128 + oc) * 1024) + px4) = s;
    } else {
#pragma unroll
        for (int p = 0; p < 8; ++p) {
            float4 u = *((const float4*)(p7 + (((size_t)side * 8 + p) * 8 + b) * 65536 + (size_t)oc * 1024) + px4);
            s.x += u.x; s.y += u.y; s.z += u.z; s.w += u.w;
        }
        *((float4*)(outb + ((size_t)b * 256 + 192 + oc) * 1024) + px4) = s;
    }
}

// ===========================================================================
// Fused QK^T + softmax -> vis (validated R4/R6).
// ===========================================================================
__global__ __launch_bounds__(512) void qk_sm_kernel(const u16* __restrict__ qbt,
                                                    const u16* __restrict__ kbt,
                                                    float* __restrict__ vis)
{
    __shared__ u16 kf[32 * 512];
    __shared__ u16 qf[4 * 512];
    __shared__ float redM[32 * 8];
    __shared__ float redS[32 * 8];
    const int t = threadIdx.x;
    const int bx = blockIdx.x;          // 8b*4h*32lt = 1024
    const int b = bx >> 7, h = (bx >> 5) & 3, l0 = (bx & 31) * 32;
    const u16* qtp = qbt + ((size_t)(b * 4 + h)) * 1024 * 64;
    const u16* ktp = kbt + ((size_t)(b * 4 + h)) * 1024 * 64;

    if (t < 256) {
        int r = t & 31, dblk = t >> 5;
        int4 pk = *(const int4*)&qtp[(size_t)(l0 + r) * 64 + dblk * 8];
        *(int4*)&qf[(((r >> 4) * 2 + (dblk >> 2)) * 64 + (dblk & 3) * 16 + (r & 15)) * 8] = pk;
    }
    __syncthreads();

    const int w = t >> 6, l = t & 63, ln = l & 15, lg = l >> 4;
    bf16x8 a[2][2];
#pragma unroll
    for (int fr = 0; fr < 2; ++fr)
#pragma unroll
        for (int ks = 0; ks < 2; ++ks)
            a[fr][ks] = *(const bf16x8*)&qf[((fr * 2 + ks) * 64 + l) * 8];

    f32x4 acc[2][4][2];
#pragma unroll
    for (int fr = 0; fr < 2; ++fr)
#pragma unroll
        for (int cc = 0; cc < 4; ++cc)
#pragma unroll
            for (int f = 0; f < 2; ++f) acc[fr][cc][f] = (f32x4){0.f, 0.f, 0.f, 0.f};

#pragma unroll
    for (int cc = 0; cc < 4; ++cc) {
        __syncthreads();
#pragma unroll
        for (int it = 0; it < 4; ++it) {
            int unit = it * 512 + t;
            int sl = unit & 255, dblk = unit >> 8;
            int4 pk = *(const int4*)&ktp[(size_t)(cc * 256 + sl) * 64 + dblk * 8];
            *(int4*)&kf[(((sl >> 4) * 2 + (dblk >> 2)) * 64 + (dblk & 3) * 16 + (sl & 15)) * 8] = pk;
        }
        __syncthreads();
#pragma unroll
        for (int f = 0; f < 2; ++f) {
            int fg = (w * 2 + f) * 2;
            bf16x8 b0 = *(const bf16x8*)&kf[((fg + 0) * 64 + l) * 8];
            bf16x8 b1 = *(const bf16x8*)&kf[((fg + 1) * 64 + l) * 8];
#pragma unroll
            for (int fr = 0; fr < 2; ++fr) {
                acc[fr][cc][f] = __builtin_amdgcn_mfma_f32_16x16x32_bf16(a[fr][0], b0, acc[fr][cc][f], 0, 0, 0);
                acc[fr][cc][f] = __builtin_amdgcn_mfma_f32_16x16x32_bf16(a[fr][1], b1, acc[fr][cc][f], 0, 0, 0);
            }
        }
    }

#pragma unroll
    for (int fr = 0; fr < 2; ++fr)
#pragma unroll
        for (int cc = 0; cc < 4; ++cc)
#pragma unroll
            for (int f = 0; f < 2; ++f)
#pragma unroll
                for (int e = 0; e < 4; ++e) acc[fr][cc][f][e] *= 0.125f;

    float rmax[2][4];
#pragma unroll
    for (int fr = 0; fr < 2; ++fr)
#pragma unroll
        for (int reg = 0; reg < 4; ++reg) {
            float m = -1e30f;
#pragma unroll
            for (int cc = 0; cc < 4; ++cc)
#pragma unroll
                for (int f = 0; f < 2; ++f) m = fmaxf(m, acc[fr][cc][f][reg]);
#pragma unroll
            for (int off = 1; off < 16; off <<= 1) m = fmaxf(m, __shfl_xor(m, off));
            if (ln == 0) redM[(fr * 16 + lg * 4 + reg) * 8 + w] = m;
            rmax[fr][reg] = m;
        }
    __syncthreads();
#pragma unroll
    for (int fr = 0; fr < 2; ++fr)
#pragma unroll
        for (int reg = 0; reg < 4; ++reg) {
            int r = fr * 16 + lg * 4 + reg;
            float m = redM[r * 8];
#pragma unroll
            for (int ww = 1; ww < 8; ++ww) m = fmaxf(m, redM[r * 8 + ww]);
            rmax[fr][reg] = m;
        }
#pragma unroll
    for (int fr = 0; fr < 2; ++fr)
#pragma unroll
        for (int reg = 0; reg < 4; ++reg) {
            float s = 0.f;
            float m = rmax[fr][reg];
#pragma unroll
            for (int cc = 0; cc < 4; ++cc)
#pragma unroll
                for (int f = 0; f < 2; ++f) {
                    float e = __expf(acc[fr][cc][f][reg] - m);
                    acc[fr][cc][f][reg] = e;
                    s += e;
                }
#pragma unroll
            for (int off = 1; off < 16; off <<= 1) s += __shfl_xor(s, off);
            if (ln == 0) redS[(fr * 16 + lg * 4 + reg) * 8 + w] = s;
        }
    __syncthreads();
    float* visp = vis + (((size_t)(b * 4 + h)) << 20);
#pragma unroll
    for (int fr = 0; fr < 2; ++fr)
#pragma unroll
        for (int reg = 0; reg < 4; ++reg) {
            int r = fr * 16 + lg * 4 + reg;
            float s = redS[r * 8] + redS[r * 8 + 1] + redS[r * 8 + 2] + redS[r * 8 + 3]
                    + redS[r * 8 + 4] + redS[r * 8 + 5] + redS[r * 8 + 6] + redS[r * 8 + 7];
            float inv = 1.f / s;
            float* vr = visp + (size_t)(l0 + r) * 1024 + w * 32 + ln;
#pragma unroll
            for (int cc = 0; cc < 4; ++cc)
#pragma unroll
                for (int f = 0; f < 2; ++f)
                    vr[cc * 256 + f * 16] = acc[fr][cc][f][reg] * inv;
        }
}

// ---------------------------------------------------------------------------
// Linear attention (validated R2).
// ---------------------------------------------------------------------------
__global__ __launch_bounds__(256) void kv_kernel(const float* __restrict__ k,
                                                 const float* __restrict__ v,
                                                 float* __restrict__ KVp,
                                                 float* __restrict__ Ksump)
{
    __shared__ float4 Kt4[64*17];
    __shared__ float4 Vt4[64*16];
    float* Kt = (float*)Kt4;
    float* Vt = (float*)Vt4;
    const int t = threadIdx.x;
    const int bx = blockIdx.x;
    const int b = bx >> 4, h = (bx >> 2) & 3, ch = bx & 3;
    const float* kb = k + ((size_t)b*256 + h*64)*1024 + ch*256;
    const float* vb = v + ((size_t)b*256 + h*64)*1024 + ch*256;
    const int d = t >> 2, v0 = (t & 3) * 16;
    float4 acc[4];
#pragma unroll
    for (int j = 0; j < 4; ++j) acc[j] = make_float4(0.f, 0.f, 0.f, 0.f);
    float ks = 0.f;
    for (int st = 0; st < 4; ++st) {
        __syncthreads();
        {
            int dd = t >> 2, r0 = (t & 3) * 16;
#pragma unroll
            for (int mm = 0; mm < 4; ++mm) {
                float4 kv = *(const float4*)(kb + dd*1024 + st*64 + r0 + mm*4);
                Kt[(r0+mm*4+0)*68 + dd] = elu1(kv.x);
                Kt[(r0+mm*4+1)*68 + dd] = elu1(kv.y);
                Kt[(r0+mm*4+2)*68 + dd] = elu1(kv.z);
                Kt[(r0+mm*4+3)*68 + dd] = elu1(kv.w);
                float4 vv = *(const float4*)(vb + dd*1024 + st*64 + r0 + mm*4);
                Vt[(r0+mm*4+0)*64 + dd] = vv.x;
                Vt[(r0+mm*4+1)*64 + dd] = vv.y;
                Vt[(r0+mm*4+2)*64 + dd] = vv.z;
                Vt[(r0+mm*4+3)*64 + dd] = vv.w;
            }
        }
        __syncthreads();
#pragma unroll 8
        for (int s = 0; s < 64; ++s) {
            float kf = Kt[s*68 + d];
            const float4* vp = (const float4*)(Vt + s*64 + v0);
#pragma unroll
            for (int j = 0; j < 4; ++j) {
                float4 vv = vp[j];
                acc[j].x += kf*vv.x; acc[j].y += kf*vv.y;
                acc[j].z += kf*vv.z; acc[j].w += kf*vv.w;
            }
        }
        if (t < 64) {
#pragma unroll 8
            for (int s = 0; s < 64; ++s) ks += Kt[s*68 + t];
        }
    }
    float* op = KVp + ((size_t)((ch*32 + b*4 + h)*64 + d))*64 + v0;
#pragma unroll
    for (int j = 0; j < 4; ++j) ((float4*)op)[j] = acc[j];
    if (t < 64) Ksump[(size_t)(ch*32 + b*4 + h)*64 + t] = ks;
}

__global__ __launch_bounds__(256) void msg_kernel(const float* __restrict__ q,
                                                  const float* __restrict__ KVp,
                                                  const float* __restrict__ Ksump,
                                                  float* __restrict__ msg)
{
    __shared__ float4 kvl4[4*1028];
    __shared__ float ksl[4*65];
    float* kvl = (float*)kvl4;
    const int t = threadIdx.x;
    const int bx = blockIdx.x;
    const int b = bx >> 4;
    const int l0 = (bx & 15) * 64;
    for (int m = 0; m < 64; ++m) {
        int idx = t + 256*m;
        int hh = idx >> 12, dd = (idx >> 6) & 63, vv = idx & 63;
        float s = 0.f;
#pragma unroll
        for (int ch = 0; ch < 4; ++ch)
            s += KVp[(size_t)((ch*32 + b*4))*4096 + idx];
        kvl[hh*4112 + dd*64 + vv] = s;
    }
    {
        float s = 0.f;
#pragma unroll
        for (int ch = 0; ch < 4; ++ch)
            s += Ksump[(size_t)(ch*32 + b*4)*64 + t];
        ksl[(t >> 6)*65 + (t & 63)] = s;
    }
    __syncthreads();
    const int h = t & 3, l = l0 + (t >> 2);
    const float* qb = q + ((size_t)b*256 + h*64)*1024 + l;
    float qf[64];
#pragma unroll
    for (int dd = 0; dd < 64; ++dd) qf[dd] = elu1(qb[dd*1024]);
    float zd = 1e-6f;
#pragma unroll
    for (int dd = 0; dd < 64; ++dd) zd += qf[dd] * ksl[h*65 + dd];
    const float Z = 1.f / zd;
    float* op = msg + ((size_t)(b*1024 + l))*256 + h*64;
    for (int c0 = 0; c0 < 64; c0 += 16) {
        float4 a[4];
#pragma unroll
        for (int j = 0; j < 4; ++j) a[j] = make_float4(0.f, 0.f, 0.f, 0.f);
#pragma unroll
        for (int dd = 0; dd < 64; ++dd) {
            float qv = qf[dd];
            const float4* kp = (const float4*)(kvl + h*4112 + dd*64 + c0);
#pragma unroll
            for (int j = 0; j < 4; ++j) {
                float4 kk = kp[j];
                a[j].x += qv*kk.x; a[j].y += qv*kk.y;
                a[j].z += qv*kk.z; a[j].w += qv*kk.w;
            }
        }
#pragma unroll
        for (int j = 0; j < 4; ++j) {
            a[j].x *= Z; a[j].y *= Z; a[j].z *= Z; a[j].w *= Z;
            ((float4*)(op + c0))[j] = a[j];
        }
    }
}

__global__ __launch_bounds__(256) void merge_ln1_kernel(const float* __restrict__ msg,
                                                        const float* __restrict__ Wm,
                                                        const float* __restrict__ g1,
                                                        const float* __restrict__ b1,
                                                        float* __restrict__ msgm)
{
    __shared__ float4 mL4[16*65];
    __shared__ float mv[32];
    float* mL = (float*)mL4;
    const int t = threadIdx.x;
    const size_t base = (size_t)blockIdx.x * 16;
    {
        int r = t >> 4, cb = t & 15;
#pragma unroll
        for (int j = 0; j < 16; ++j)
            mL[r*260 + cb + 16*j] = msg[(base + r)*256 + cb + 16*j];
    }
    __syncthreads();
    float acc[16];
#pragma unroll
    for (int r = 0; r < 16; ++r) acc[r] = 0.f;
    for (int i = 0; i < 256; i += 4) {
        float w0 = Wm[(size_t)(i+0)*256 + t];
        float w1 = Wm[(size_t)(i+1)*256 + t];
        float w2 = Wm[(size_t)(i+2)*256 + t];
        float w3 = Wm[(size_t)(i+3)*256 + t];
#pragma unroll
        for (int r = 0; r < 16; ++r) {
            float4 m4 = mL4[r*65 + (i >> 2)];
            acc[r] += m4.x*w0 + m4.y*w1 + m4.z*w2 + m4.w*w3;
        }
    }
    __syncthreads();
#pragma unroll
    for (int r = 0; r < 16; ++r) mL[r*260 + t] = acc[r];
    __syncthreads();
    {
        int wid = t >> 6, lane = t & 63;
#pragma unroll
        for (int rr = 0; rr < 4; ++rr) {
            int r = wid*4 + rr;
            float s1 = 0.f, s2 = 0.f;
#pragma unroll
            for (int m = 0; m < 4; ++m) {
                float vv = mL[r*260 + lane + 64*m];
                s1 += vv; s2 += vv*vv;
            }
#pragma unroll
            for (int off = 1; off < 64; off <<= 1) {
                s1 += __shfl_xor(s1, off);
                s2 += __shfl_xor(s2, off);
            }
            if (lane == 0) {
                float mean = s1 * (1.f/256.f);
                float var  = s2 * (1.f/256.f) - mean*mean;
                mv[r*2]   = mean;
                mv[r*2+1] = rsqrtf(var + 1e-5f);
            }
        }
    }
    __syncthreads();
    const float gg = g1[t], bb = b1[t];
#pragma unroll
    for (int r = 0; r < 16; ++r) {
        float val = (mL[r*260 + t] - mv[r*2]) * mv[r*2+1] * gg + bb;
        msgm[(base + r)*256 + t] = val;
    }
}

// ===========================================================================
// FF via MFMA (validated R4).
// ===========================================================================
__global__ __launch_bounds__(256) void ff_mfma_kernel(
    const float* __restrict__ x, const float* __restrict__ msgm,
    const u16* __restrict__ w1p, const u16* __restrict__ w2p,
    const float* __restrict__ g2, const float* __restrict__ b2,
    float* __restrict__ out)
{
    __shared__ u16 tile[32 * 520];
    __shared__ float redS[32 * 4];
    __shared__ float redQ[32 * 4];
    float* tf = (float*)tile;
    const int t = threadIdx.x;
    const int base = blockIdx.x * 32;       // 256 blocks
    const int b = base >> 10, l0 = base & 1023;
    const int w = t >> 6, l = t & 63, ln = l & 15, lg = l >> 4;

    {
        int rr = t & 31, cg = t >> 5;
        for (int cci = 0; cci < 32; ++cci) {
            int c = cci * 8 + cg;
            float v = x[((size_t)b * 256 + c) * 1024 + l0 + rr];
            tile[rr * 520 + c] = f2bf(v);
        }
        int r = t >> 3, cb = (t & 7) * 32;
#pragma unroll
        for (int i = 0; i < 8; ++i) {
            float4 v = *(const float4*)&msgm[((size_t)(base + r)) * 256 + cb + i * 4];
            u32 p0 = (u32)f2bf(v.x) | ((u32)f2bf(v.y) << 16);
            u32 p1 = (u32)f2bf(v.z) | ((u32)f2bf(v.w) << 16);
            *(u32*)&tile[r * 520 + 256 + cb + i * 4] = p0;
            *(u32*)&tile[r * 520 + 256 + cb + i * 4 + 2] = p1;
        }
    }
    __syncthreads();

    f32x4 acc[2][8];
#pragma unroll
    for (int fr = 0; fr < 2; ++fr)
#pragma unroll
        for (int fc = 0; fc < 8; ++fc) acc[fr][fc] = (f32x4){0.f, 0.f, 0.f, 0.f};
    for (int ks = 0; ks < 16; ++ks) {
        bf16x8 a0 = *(const bf16x8*)&tile[(ln) * 520 + ks * 32 + lg * 8];
        bf16x8 a1 = *(const bf16x8*)&tile[(16 + ln) * 520 + ks * 32 + lg * 8];
#pragma unroll
        for (int fc = 0; fc < 8; ++fc) {
            bf16x8 bb = *(const bf16x8*)&w1p[((size_t)(ks * 32 + w * 8 + fc) * 64 + l) * 8];
            acc[0][fc] = __builtin_amdgcn_mfma_f32_16x16x32_bf16(a0, bb, acc[0][fc], 0, 0, 0);
            acc[1][fc] = __builtin_amdgcn_mfma_f32_16x16x32_bf16(a1, bb, acc[1][fc], 0, 0, 0);
        }
    }
    __syncthreads();
#pragma unroll
    for (int fr = 0; fr < 2; ++fr)
#pragma unroll
        for (int fc = 0; fc < 8; ++fc)
#pragma unroll
            for (int reg = 0; reg < 4; ++reg) {
                int r = fr * 16 + lg * 4 + reg;
                int c = w * 128 + fc * 16 + ln;
                tile[r * 520 + c] = f2bf(fmaxf(acc[fr][fc][reg], 0.f));
            }
    __syncthreads();

    f32x4 acc2[2][4];
#pragma unroll
    for (int fr = 0; fr < 2; ++fr)
#pragma unroll
        for (int fc = 0; fc < 4; ++fc) acc2[fr][fc] = (f32x4){0.f, 0.f, 0.f, 0.f};
    for (int ks = 0; ks < 16; ++ks) {
        bf16x8 a0 = *(const bf16x8*)&tile[(ln) * 520 + ks * 32 + lg * 8];
        bf16x8 a1 = *(const bf16x8*)&tile[(16 + ln) * 520 + ks * 32 + lg * 8];
#pragma unroll
        for (int fc = 0; fc < 4; ++fc) {
            bf16x8 bb = *(const bf16x8*)&w2p[((size_t)(ks * 16 + w * 4 + fc) * 64 + l) * 8];
            acc2[0][fc] = __builtin_amdgcn_mfma_f32_16x16x32_bf16(a0, bb, acc2[0][fc], 0, 0, 0);
            acc2[1][fc] = __builtin_amdgcn_mfma_f32_16x16x32_bf16(a1, bb, acc2[1][fc], 0, 0, 0);
        }
    }
#pragma unroll
    for (int fr = 0; fr < 2; ++fr)
#pragma unroll
        for (int reg = 0; reg < 4; ++reg) {
            float s = 0.f, qsum = 0.f;
#pragma unroll
            for (int fc = 0; fc < 4; ++fc) {
                float v = acc2[fr][fc][reg];
                s += v; qsum += v * v;
            }
#pragma unroll
            for (int off = 1; off < 16; off <<= 1) {
                s += __shfl_xor(s, off);
                qsum += __shfl_xor(qsum, off);
            }
            if (ln == 0) {
                int r = fr * 16 + lg * 4 + reg;
                redS[r * 4 + w] = s;
                redQ[r * 4 + w] = qsum;
            }
        }
    __syncthreads();
    float mean[2][4], rstd[2][4];
#pragma unroll
    for (int fr = 0; fr < 2; ++fr)
#pragma unroll
        for (int reg = 0; reg < 4; ++reg) {
            int r = fr * 16 + lg * 4 + reg;
            float s = redS[r * 4] + redS[r * 4 + 1] + redS[r * 4 + 2] + redS[r * 4 + 3];
            float qs = redQ[r * 4] + redQ[r * 4 + 1] + redQ[r * 4 + 2] + redQ[r * 4 + 3];
            float m = s * (1.f / 256.f);
            mean[fr][reg] = m;
            rstd[fr][reg] = rsqrtf(qs * (1.f / 256.f) - m * m + 1e-5f);
        }
#pragma unroll
    for (int fc = 0; fc < 4; ++fc) {
        int c = w * 64 + fc * 16 + ln;
        float gg = g2[c], bb = b2[c];
#pragma unroll
        for (int fr = 0; fr < 2; ++fr)
#pragma unroll
            for (int reg = 0; reg < 4; ++reg) {
                int r = fr * 16 + lg * 4 + reg;
                tf[r * 260 + c] = (acc2[fr][fc][reg] - mean[fr][reg]) * rstd[fr][reg] * gg + bb;
            }
    }
    __syncthreads();
    {
        const float* xp = x + ((size_t)b * 256 + t) * 1024 + l0;
        float* op = out + ((size_t)b * 256 + t) * 1024 + l0;
#pragma unroll
        for (int i = 0; i < 8; ++i) {
            float4 xv = *(const float4*)(xp + i * 4);
            float4 o;
            o.x = xv.x + tf[(i * 4 + 0) * 260 + t];
            o.y = xv.y + tf[(i * 4 + 1) * 260 + t];
            o.z = xv.z + tf[(i * 4 + 2) * 260 + t];
            o.w = xv.w + tf[(i * 4 + 3) * 260 + t];
            *(float4*)(op + i * 4) = o;
        }
    }
}

// ---------------------------------------------------------------------------
extern "C" void kernel_launch(void* const* d_in, const int* in_sizes, int n_in,
                              void* d_out, int out_size, void* d_ws, size_t ws_size,
                              hipStream_t stream)
{
    const float* x    = (const float*)d_in[0];
    const float* src  = (const float*)d_in[1];
    const float* Wq   = (const float*)d_in[2];
    const float* Wk1  = (const float*)d_in[3];
    const float* Wk3  = (const float*)d_in[4];
    const float* Wk5  = (const float*)d_in[5];
    const float* Wk7  = (const float*)d_in[6];
    const float* Wv1  = (const float*)d_in[7];
    const float* Wv3  = (const float*)d_in[8];
    const float* Wv5  = (const float*)d_in[9];
    const float* Wv7  = (const float*)d_in[10];
    const float* Wm   = (const float*)d_in[11];
    const float* g1   = (const float*)d_in[12];
    const float* b1   = (const float*)d_in[13];
    const float* g2   = (const float*)d_in[14];
    const float* b2   = (const float*)d_in[15];
    const float* W1   = (const float*)d_in[16];
    const float* W2   = (const float*)d_in[17];

    float* out = (float*)d_out;
    float* vis = out + 2097152;          // [b,h,l,s] (33.55M floats)

    // Conv partials in vis region (dead until qk_sm overwrites all of it).
    float* p5 = vis;                     // [2][4][8][64][1024] = 4.19M floats
    float* p7 = vis + 4194304;           // [2][8][8][64][1024] = 8.39M floats

    // ws extent+lifetime map (float offsets; audited R6):
    //  qb    [0,        2097152)  conv..msg_kernel
    //  kb    [2097152,  4194304)  conv..kv/cast_qk
    //  vb    [4194304,  6291456)  conv..kv
    //  wpack [6291456,  7962624)  repack..conv
    //    then w1p [6291456, 6422528) repack_ff..ff
    //         w2p [6422528, 6488064) repack_ff..ff
    //         qbt [6488064, 7536640) cast_qk..qk_sm
    //         kbt [7536640, 8585216) cast_qk..qk_sm (overlaps dead xbh)
    //  xbh   [7962624,  9011200)  cast_src..conv
    //  sbh   [9011200, 10059776)  cast_src..conv
    //    then msg [7962624, 10059776) msg_kernel..merge
    //  msgm  [10059776, 12156928)  merge..ff
    //  KVp   [12156928, 12681216), Ksump [12681216, 12689408)
    float* ws    = (float*)d_ws;
    float* qb    = ws;
    float* kb    = ws + 2097152;
    float* vb    = ws + 4194304;
    u16*   wpack = (u16*)(ws + 6291456);
    u16*   w1p   = (u16*)(ws + 6291456);
    u16*   w2p   = (u16*)(ws + 6422528);
    u16*   qbt   = (u16*)(ws + 6488064);
    u16*   kbt   = (u16*)(ws + 7536640);
    u16*   xbh   = (u16*)(ws + 7962624);
    u16*   sbh   = (u16*)(ws + 9011200);
    float* msg   = ws + 7962624;
    float* msgm  = ws + 10059776;
    float* KVp   = ws + 12156928;
    float* Ksump = ws + 12681216;

    repack_kernel   <<<1632, 256, 0, stream>>>(Wq, Wk1, Wk3, Wk5, Wk7,
                                               Wv1, Wv3, Wv5, Wv7, wpack);
    cast_src_kernel <<<1024, 256, 0, stream>>>(x, src, xbh, sbh);
    conv_mfma_kernel<<<512,  512, 0, stream>>>(xbh, sbh, wpack, qb, kb, vb, p5, p7);
    reduce_kernel   <<<2048, 256, 0, stream>>>(p5, p7, kb, vb);
    repack_ff_kernel<<<192,  256, 0, stream>>>(W1, W2, w1p, w2p);
    cast_qk_kernel  <<<1024, 256, 0, stream>>>(qb, kb, qbt, kbt);
    qk_sm_kernel    <<<1024, 512, 0, stream>>>(qbt, kbt, vis);
    kv_kernel       <<<128,  256, 0, stream>>>(kb, vb, KVp, Ksump);
    msg_kernel      <<<128,  256, 0, stream>>>(qb, KVp, Ksump, msg);
    merge_ln1_kernel<<<512,  256, 0, stream>>>(msg, Wm, g1, b1, msgm);
    ff_mfma_kernel  <<<256,  256, 0, stream>>>(x, msgm, w1p, w2p, g2, b2, out);
}